// Round 2
// baseline (48546.548 us; speedup 1.0000x reference)
//
#include <hip/hip_runtime.h>
#include <stdint.h>

// ---------------------------------------------------------------------------
// PointNet++ forward, MI355X. Round 2: FPS rewrite.
//   - k_sort: Morton-bin counting sort per level (pruning locality).
//   - k_fps2: 4-wave subcell-pruned FPS, DPP u64 argmax with exact tie-break,
//     per-subcell top-2 champions, double-accept (2 selections per barrier
//     round when provably exact).
//   - SA/FP/prep unchanged (validated round 1).
// All reference-sensitive math uses explicit RN intrinsics (no contraction).
// ---------------------------------------------------------------------------

#define DEV static __device__ __forceinline__

DEV float fadd_(float a, float b){ return __fadd_rn(a,b); }
DEV float fsub_(float a, float b){ return __fsub_rn(a,b); }
DEV float fmul_(float a, float b){ return __fmul_rn(a,b); }
DEV float fdiv_(float a, float b){ return __fdiv_rn(a,b); }

DEV float dot3(float ax,float ay,float az,float bx,float by,float bz){
  return fmaf(az,bz, fmaf(ay,by, __fmul_rn(ax,bx)));
}
DEV float sqd(float na, float nb, float d){
  float t = __fadd_rn(na, nb);
  float u = __fmul_rn(2.0f, d);
  return fmaxf(__fsub_rn(t, u), 0.0f);
}

// ---------------- DPP wave-reduce helpers ----------------------------------
// Canonical GCN sequence: row_shr 1/2/4/8 then row_bcast15 (rm 0xa),
// row_bcast31 (rm 0xc); total lands in lane 63. bound_ctrl=0 + old-preserve
// makes invalid lanes keep the accumulator.

#define DPPI(v,ctrl,rm) __builtin_amdgcn_update_dpp((v),(v),(ctrl),(rm),0xf,false)
#define DPPF(v,ctrl,rm) __int_as_float(__builtin_amdgcn_update_dpp(__float_as_int(v),__float_as_int(v),(ctrl),(rm),0xf,false))

#define DPP_STEP_U64(hi,lo,ctrl,rm) { \
  uint32_t nh_=(uint32_t)DPPI((int)(hi),ctrl,rm); \
  uint32_t nl_=(uint32_t)DPPI((int)(lo),ctrl,rm); \
  bool tk_=(nh_>(hi))||((nh_==(hi))&&(nl_>(lo))); \
  (hi)=tk_?nh_:(hi); (lo)=tk_?nl_:(lo); }

// full-wave max of packed (hi,lo) u64; result broadcast to all lanes
DEV void wmax64(uint32_t &hi, uint32_t &lo){
  DPP_STEP_U64(hi,lo,0x111,0xf)
  DPP_STEP_U64(hi,lo,0x112,0xf)
  DPP_STEP_U64(hi,lo,0x114,0xf)
  DPP_STEP_U64(hi,lo,0x118,0xf)
  DPP_STEP_U64(hi,lo,0x142,0xa)
  DPP_STEP_U64(hi,lo,0x143,0xc)
  hi = (uint32_t)__builtin_amdgcn_readlane((int)hi, 63);
  lo = (uint32_t)__builtin_amdgcn_readlane((int)lo, 63);
}

#define MSTEP(ctrl,rm) { float a_; \
  a_=DPPF(lx,ctrl,rm); lx=fminf(lx,a_); \
  a_=DPPF(ly,ctrl,rm); ly=fminf(ly,a_); \
  a_=DPPF(lz,ctrl,rm); lz=fminf(lz,a_); \
  a_=DPPF(hx,ctrl,rm); hx=fmaxf(hx,a_); \
  a_=DPPF(hy,ctrl,rm); hy=fmaxf(hy,a_); \
  a_=DPPF(hz,ctrl,rm); hz=fmaxf(hz,a_); }

DEV void wredminmax(float &lx,float &ly,float &lz,float &hx,float &hy,float &hz){
  MSTEP(0x111,0xf) MSTEP(0x112,0xf) MSTEP(0x114,0xf) MSTEP(0x118,0xf)
  MSTEP(0x142,0xa) MSTEP(0x143,0xc)
  lx=__int_as_float(__builtin_amdgcn_readlane(__float_as_int(lx),63));
  ly=__int_as_float(__builtin_amdgcn_readlane(__float_as_int(ly),63));
  lz=__int_as_float(__builtin_amdgcn_readlane(__float_as_int(lz),63));
  hx=__int_as_float(__builtin_amdgcn_readlane(__float_as_int(hx),63));
  hy=__int_as_float(__builtin_amdgcn_readlane(__float_as_int(hy),63));
  hz=__int_as_float(__builtin_amdgcn_readlane(__float_as_int(hz),63));
}

// conservative point-to-bbox squared distance (RN; margin applied by caller)
DEV float bbd2(float sx,float sy,float sz,
               float lx,float ly,float lz,float hx,float hy,float hz){
  float dx = fmaxf(fmaxf(fsub_(lx,sx), fsub_(sx,hx)), 0.0f);
  float dy = fmaxf(fmaxf(fsub_(ly,sy), fsub_(sy,hy)), 0.0f);
  float dz = fmaxf(fmaxf(fsub_(lz,sz), fsub_(sz,hz)), 0.0f);
  return fadd_(fadd_(fmul_(dx,dx),fmul_(dy,dy)),fmul_(dz,dz));
}

// ---------------------------------------------------------------------------
// prep: pos -> float4(x,y,z,|p|^2)  and  h0 = lin_in MLP(x)
// ---------------------------------------------------------------------------
__global__ __launch_bounds__(256) void k_prep(
    const float* __restrict__ x, const float* __restrict__ pos,
    const float* __restrict__ W0, const float* __restrict__ b0,
    const float* __restrict__ W1, const float* __restrict__ b1,
    float4* __restrict__ pos4, float* __restrict__ h_out, int n)
{
  __shared__ float sW0[256], sb0[16], sW1[256], sb1[16];
  int tid = threadIdx.x;
  sW0[tid] = W0[tid];
  sW1[tid] = W1[tid];
  if (tid < 16){ sb0[tid] = b0[tid]; sb1[tid] = b1[tid]; }
  __syncthreads();
  int p = blockIdx.x*256 + tid;
  if (p >= n) return;

  float px = pos[3*p], py = pos[3*p+1], pz = pos[3*p+2];
  float nrm = fadd_(fadd_(fmul_(px,px), fmul_(py,py)), fmul_(pz,pz));
  pos4[p] = make_float4(px,py,pz,nrm);

  const float4* xr = (const float4*)(x + (size_t)p*16);
  float4 v0 = xr[0], v1 = xr[1], v2 = xr[2], v3 = xr[3];
  float xin[16] = {v0.x,v0.y,v0.z,v0.w, v1.x,v1.y,v1.z,v1.w,
                   v2.x,v2.y,v2.z,v2.w, v3.x,v3.y,v3.z,v3.w};
  float h1[16];
  #pragma unroll
  for (int o=0;o<16;o++){
    float acc = fmul_(xin[0], sW0[o]);
    #pragma unroll
    for (int k=1;k<16;k++) acc = fmaf(xin[k], sW0[k*16+o], acc);
    h1[o] = fmaxf(fadd_(acc, sb0[o]), 0.0f);
  }
  float h2[16];
  #pragma unroll
  for (int o=0;o<16;o++){
    float acc = fmul_(h1[0], sW1[o]);
    #pragma unroll
    for (int k=1;k<16;k++) acc = fmaf(h1[k], sW1[k*16+o], acc);
    h2[o] = fmaxf(fadd_(acc, sb1[o]), 0.0f);
  }
  float4* hw = (float4*)(h_out + (size_t)p*16);
  hw[0] = make_float4(h2[0], h2[1], h2[2], h2[3]);
  hw[1] = make_float4(h2[4], h2[5], h2[6], h2[7]);
  hw[2] = make_float4(h2[8], h2[9], h2[10],h2[11]);
  hw[3] = make_float4(h2[12],h2[13],h2[14],h2[15]);
}

// ---------------------------------------------------------------------------
// k_sort: Morton counting sort (16^3 cells). Output w = bits(natural index).
// Order within a bin is arbitrary (does not affect results: FPS tie-breaks
// by natural index carried in w; subcell membership only affects pruning).
// ---------------------------------------------------------------------------
DEV uint32_t expand4(uint32_t v){
  return (v&1u) | ((v&2u)<<2) | ((v&4u)<<4) | ((v&8u)<<6);
}
DEV int cellc(float v){
  int c = (int)(v*0.5f);
  return c < 0 ? 0 : (c > 15 ? 15 : c);
}
DEV uint32_t mkey(float4 p){
  return expand4((uint32_t)cellc(p.x))
       | (expand4((uint32_t)cellc(p.y))<<1)
       | (expand4((uint32_t)cellc(p.z))<<2);
}

__global__ __launch_bounds__(1024) void k_sort(
  const float4* __restrict__ nat, float4* __restrict__ srt,
  int* __restrict__ rank0, int n)
{
  __shared__ uint32_t hist[4096];
  __shared__ uint32_t gsum[1024];
  int tid = threadIdx.x;
  for (int i=tid;i<4096;i+=1024) hist[i]=0u;
  __syncthreads();
  for (int i=tid;i<n;i+=1024){
    float4 p = nat[i];
    atomicAdd(&hist[mkey(p)], 1u);
  }
  __syncthreads();
  uint32_t h0=hist[4*tid],h1=hist[4*tid+1],h2=hist[4*tid+2],h3=hist[4*tid+3];
  gsum[tid] = h0+h1+h2+h3;
  __syncthreads();
  for (int off=1; off<1024; off<<=1){
    uint32_t v = gsum[tid];
    uint32_t a = (tid>=off)? gsum[tid-off] : 0u;
    __syncthreads();
    gsum[tid] = v + a;
    __syncthreads();
  }
  uint32_t excl = (tid>0)? gsum[tid-1] : 0u;
  hist[4*tid]   = excl;
  hist[4*tid+1] = excl + h0;
  hist[4*tid+2] = excl + h0 + h1;
  hist[4*tid+3] = excl + h0 + h1 + h2;
  __syncthreads();
  for (int i=tid;i<n;i+=1024){
    float4 p = nat[i];
    uint32_t r = atomicAdd(&hist[mkey(p)], 1u);
    srt[r] = make_float4(p.x, p.y, p.z, __uint_as_float((uint32_t)i));
    if (i==0) *rank0 = (int)r;
  }
}

// ---------------------------------------------------------------------------
// k_fps2: subcell-pruned FPS, exact replication of the reference scan.
// 256 threads (4 waves). Subcell = 64 consecutive sorted points, owned by one
// wave. Packed order key: (mind_bits<<32)|(~natidx<<16)|sortedpos -> u64 max
// == (value desc, natidx asc). Double-accept when provably exact.
// ---------------------------------------------------------------------------
__global__ __launch_bounds__(256) void k_fps2(
    const float4* __restrict__ sp4,   // sorted points, w = bits(natidx)
    const int* __restrict__ rank0p,
    float4* __restrict__ samp,        // selection-order output, w = |p|^2
    int n, int m)
{
  __shared__ float mind[16384];
  __shared__ unsigned long long xch[2][8];
  const int tid  = threadIdx.x;
  const int w    = tid >> 6, lane = tid & 63;
  const int S    = n >> 8;            // subcells per wave
  const int sub0 = w * S;

  for (int i=tid;i<n;i+=256) mind[i] = __builtin_inff();

  // per-lane bbox of subcell `lane` (lanes >= S unused)
  float blox=0,bloy=0,bloz=0,bhix=0,bhiy=0,bhiz=0;
  for (int c=0;c<S;c++){
    float4 p = sp4[((sub0+c)<<6)|lane];
    float lx=p.x, ly=p.y, lz=p.z, hx=p.x, hy=p.y, hz=p.z;
    wredminmax(lx,ly,lz,hx,hy,hz);
    bool own = (lane==c);
    blox = own?lx:blox; bloy = own?ly:bloy; bloz = own?lz:bloz;
    bhix = own?hx:bhix; bhiy = own?hy:bhiy; bhiz = own?hz:bhiz;
  }
  __syncthreads();   // mind init visible

  // per-subcell top-2 champions (lane-held). val=inf forces round-1 update.
  uint32_t cp1h = (lane < S) ? 0x7f800000u : 0u, cp1l = 0u;
  uint32_t cp2h = 0u, cp2l = 0u;

  float c1x,c1y,c1z, c2x=0,c2y=0,c2z=0; int u2 = 0;
  {
    int r0 = *rank0p;
    float4 s0 = sp4[r0];
    c1x=s0.x; c1y=s0.y; c1z=s0.z;
    if (tid==0){
      float nr = fadd_(fadd_(fmul_(s0.x,s0.x),fmul_(s0.y,s0.y)),fmul_(s0.z,s0.z));
      samp[0] = make_float4(s0.x,s0.y,s0.z,nr);
    }
  }

  int t = 1, round = 0;
  unsigned long long ck1 = 0ull, ck2 = 0ull;  // cached wave top-2

  while (true){
    // ---- predicate: does my subcell provably not change? -----------------
    bool updp = false;
    if (lane < S){
      float cv = __uint_as_float(cp1h);   // subcell max of mind
      float d1 = bbd2(c1x,c1y,c1z, blox,bloy,bloz,bhix,bhiy,bhiz);
      updp = (fmul_(d1, 0.99999f) < cv);
      if (u2 && !updp){
        float d2 = bbd2(c2x,c2y,c2z, blox,bloy,bloz,bhix,bhiy,bhiz);
        updp = (fmul_(d2, 0.99999f) < cv);
      }
    }
    unsigned long long mask = __ballot(updp);
    if (mask){
      do {
        int k = __ffsll(mask) - 1; mask &= mask - 1;   // wave-uniform
        int g = ((sub0 + k) << 6) | lane;
        float4 p  = sp4[g];
        float mv  = mind[g];
        float dx=fsub_(p.x,c1x), dy=fsub_(p.y,c1y), dz=fsub_(p.z,c1z);
        float d2a = fadd_(fadd_(fmul_(dx,dx),fmul_(dy,dy)),fmul_(dz,dz));
        float nm  = fminf(mv, d2a);
        if (u2){
          float ex=fsub_(p.x,c2x), ey=fsub_(p.y,c2y), ez=fsub_(p.z,c2z);
          float d2b = fadd_(fadd_(fmul_(ex,ex),fmul_(ey,ey)),fmul_(ez,ez));
          nm = fminf(nm, d2b);
        }
        mind[g] = nm;
        uint32_t oidx = __float_as_uint(p.w);
        uint32_t hi = __float_as_uint(nm);
        uint32_t lo = ((~oidx & 0xFFFFu)<<16) | (uint32_t)g;
        // subcell top-2
        uint32_t s1h=hi, s1l=lo; wmax64(s1h,s1l);
        bool self = (hi==s1h) && (lo==s1l);
        uint32_t s2h = self?0u:hi, s2l = self?0u:lo;
        wmax64(s2h,s2l);
        bool own = (lane==k);
        cp1h = own?s1h:cp1h; cp1l = own?s1l:cp1l;
        cp2h = own?s2h:cp2h; cp2l = own?s2l:cp2l;
      } while (mask);
      // wave top-2 over subcell top-2s (lane owning T1 substitutes its 2nd)
      uint32_t h=cp1h, l=cp1l; wmax64(h,l);
      bool self1 = (cp1h==h) && (cp1l==l);
      uint32_t h2 = self1?cp2h:cp1h, l2 = self1?cp2l:cp1l;
      wmax64(h2,l2);
      ck1 = ((unsigned long long)h <<32) | l;
      ck2 = ((unsigned long long)h2<<32) | l2;
    }
    int par = round & 1;
    if (lane==0) xch[par][2*w]   = ck1;
    if (lane==1) xch[par][2*w+1] = ck2;
    __syncthreads();
    // ---- global top-2 (all waves redundantly) ----------------------------
    unsigned long long cnd = (lane<8) ? xch[par][lane] : 0ull;
    uint32_t qh=(uint32_t)(cnd>>32), ql=(uint32_t)cnd;
    uint32_t H=qh, L=ql; wmax64(H,L);
    bool selfg = (qh==H) && (ql==L);
    uint32_t H2 = selfg?0u:qh, L2 = selfg?0u:ql;
    wmax64(H2,L2);
    int   sp1 = (int)(L  & 0xFFFFu);
    int   sp2 = (int)(L2 & 0xFFFFu);
    float v2  = __uint_as_float(H2);
    float4 P1 = sp4[sp1];
    float4 P2 = sp4[sp2];
    // ---- accept ----------------------------------------------------------
    float qx=fsub_(P2.x,P1.x), qy=fsub_(P2.y,P1.y), qz=fsub_(P2.z,P1.z);
    float q  = fadd_(fadd_(fmul_(qx,qx),fmul_(qy,qy)),fmul_(qz,qz));
    bool acc2 = (t+1 < m) && (q >= v2);
    if (tid==0){
      float nr = fadd_(fadd_(fmul_(P1.x,P1.x),fmul_(P1.y,P1.y)),fmul_(P1.z,P1.z));
      samp[t] = make_float4(P1.x,P1.y,P1.z,nr);
    }
    if (acc2 && tid==1){
      float nr = fadd_(fadd_(fmul_(P2.x,P2.x),fmul_(P2.y,P2.y)),fmul_(P2.z,P2.z));
      samp[t+1] = make_float4(P2.x,P2.y,P2.z,nr);
    }
    t += acc2 ? 2 : 1;
    round++;
    if (t >= m) break;
    c1x=P1.x; c1y=P1.y; c1z=P1.z;
    u2 = acc2 ? 1 : 0;
    if (acc2){ c2x=P2.x; c2y=P2.y; c2z=P2.z; }
  }
}

// ---------------------------------------------------------------------------
// SA: wave per target (unchanged from round 1)
// ---------------------------------------------------------------------------
#define SA_CAP 96

__global__ __launch_bounds__(256) void k_sa(
  const float4* __restrict__ spos, int n_src,
  const float4* __restrict__ tpos,
  const float*  __restrict__ F,
  const float* __restrict__ W0, const float* __restrict__ b0,
  const float* __restrict__ W1, const float* __restrict__ b1,
  float* __restrict__ Fout)
{
  __shared__ float sW0[361], sb0[19], sW1[304], sb1[16];
  __shared__ int   nidx[4][SA_CAP];
  __shared__ float nd2[4][SA_CAP];
  int tid = threadIdx.x;
  for (int i=tid;i<361;i+=256) sW0[i]=W0[i];
  for (int i=tid;i<304;i+=256) sW1[i]=W1[i];
  if (tid<19) sb0[tid]=b0[tid];
  if (tid<16) sb1[tid]=b1[tid];
  __syncthreads();

  int wv = tid >> 6, lane = tid & 63;
  int tg = blockIdx.x*4 + wv;
  float4 tp = tpos[tg];

  int cnt = 0;
  for (int base=0; base<n_src; base+=64){
    int j = base + lane;
    float4 sp = spos[j];
    float d2 = sqd(tp.w, sp.w, dot3(tp.x,tp.y,tp.z, sp.x,sp.y,sp.z));
    bool in = (d2 <= 4.0f);
    unsigned long long mk = __ballot(in);
    int pos = cnt + __popcll(mk & ((1ull<<lane)-1ull));
    if (in && pos < SA_CAP){ nidx[wv][pos]=j; nd2[wv][pos]=d2; }
    cnt += __popcll(mk);
  }
  if (cnt > SA_CAP) cnt = SA_CAP;

  if (cnt > 32){
    uint64_t tk0=0, tk1=0;
    for (int r=0;r<32;r++){
      float bvv = 3.5e38f; int bii = 0x7fffffff; int be = 0;
      for (int e=0;e<cnt;e++){
        bool done = (e<64) ? ((tk0>>e)&1ull) : ((tk1>>(e-64))&1ull);
        if (done) continue;
        float dv = nd2[wv][e]; int di = nidx[wv][e];
        if (dv < bvv || (dv == bvv && di < bii)){ bvv=dv; bii=di; be=e; }
      }
      if (be < 64) tk0 |= (1ull<<be); else tk1 |= (1ull<<(be-64));
    }
    int myi = 0; float myd = 0.0f;
    if (lane < 32){
      int seen = 0, sel = -1;
      for (int e=0;e<cnt && sel<0;e++){
        bool s = (e<64) ? ((tk0>>e)&1ull) : ((tk1>>(e-64))&1ull);
        if (s){ if (seen == lane) sel = e; seen++; }
      }
      myi = nidx[wv][sel]; myd = nd2[wv][sel];
    }
    __builtin_amdgcn_wave_barrier();
    if (lane < 32){ nidx[wv][lane]=myi; nd2[wv][lane]=myd; }
    __builtin_amdgcn_wave_barrier();
    cnt = 32;
  }

  float in19[19];
  #pragma unroll
  for (int k=0;k<19;k++) in19[k] = 0.0f;
  if (lane < cnt){
    int j = nidx[wv][lane];
    const float4* fr = (const float4*)(F + (size_t)j*16);
    float4 a=fr[0], b=fr[1], c=fr[2], d=fr[3];
    in19[0]=a.x; in19[1]=a.y; in19[2]=a.z; in19[3]=a.w;
    in19[4]=b.x; in19[5]=b.y; in19[6]=b.z; in19[7]=b.w;
    in19[8]=c.x; in19[9]=c.y; in19[10]=c.z; in19[11]=c.w;
    in19[12]=d.x; in19[13]=d.y; in19[14]=d.z; in19[15]=d.w;
    float4 sp = spos[j];
    in19[16]=fsub_(sp.x,tp.x); in19[17]=fsub_(sp.y,tp.y); in19[18]=fsub_(sp.z,tp.z);
  }
  float h[19];
  #pragma unroll
  for (int o=0;o<19;o++){
    float acc = fmul_(in19[0], sW0[o]);
    #pragma unroll
    for (int k=1;k<19;k++) acc = fmaf(in19[k], sW0[k*19+o], acc);
    h[o] = fmaxf(fadd_(acc, sb0[o]), 0.0f);
  }
  float outv[16];
  #pragma unroll
  for (int o=0;o<16;o++){
    float acc = fmul_(h[0], sW1[o]);
    #pragma unroll
    for (int k=1;k<19;k++) acc = fmaf(h[k], sW1[k*16+o], acc);
    float v = fmaxf(fadd_(acc, sb1[o]), 0.0f);
    outv[o] = (lane < cnt) ? v : -1e30f;
  }
  #pragma unroll
  for (int o=0;o<16;o++){
    float v = outv[o];
    #pragma unroll
    for (int s=1;s<64;s<<=1) v = fmaxf(v, __shfl_xor(v, s));
    outv[o] = v;
  }
  if (lane == 0){
    float4* dst = (float4*)(Fout + (size_t)tg*16);
    dst[0] = make_float4(outv[0], outv[1], outv[2], outv[3]);
    dst[1] = make_float4(outv[4], outv[5], outv[6], outv[7]);
    dst[2] = make_float4(outv[8], outv[9], outv[10],outv[11]);
    dst[3] = make_float4(outv[12],outv[13],outv[14],outv[15]);
  }
}

// ---------------------------------------------------------------------------
// FP: wave per fine point (unchanged from round 1)
// ---------------------------------------------------------------------------
__global__ __launch_bounds__(256) void k_fp(
  const float4* __restrict__ fpos,
  const float4* __restrict__ cpos, int n_coarse,
  const float* __restrict__ Fc, const float* __restrict__ Fs,
  const float* __restrict__ W0, const float* __restrict__ b0,
  const float* __restrict__ W1, const float* __restrict__ b1,
  const float* __restrict__ loW0, const float* __restrict__ lob0,
  const float* __restrict__ loW1, const float* __restrict__ lob1,
  float* __restrict__ outp, int final_)
{
  __shared__ float sW0[1024], sb0[32], sW1[512], sb1[16];
  __shared__ float sLW0[256], sLb0[16], sLW1[32], sLb1[2];
  int tid = threadIdx.x;
  for (int i=tid;i<1024;i+=256) sW0[i]=W0[i];
  for (int i=tid;i<512;i+=256)  sW1[i]=W1[i];
  if (tid<32) sb0[tid]=b0[tid];
  if (tid<16) sb1[tid]=b1[tid];
  if (final_){
    sLW0[tid & 255] = loW0[tid & 255];
    if (tid<16) sLb0[tid]=lob0[tid];
    if (tid<32) sLW1[tid]=loW1[tid];
    if (tid<2)  sLb1[tid]=lob1[tid];
  }
  __syncthreads();

  int wv = tid >> 6, lane = tid & 63;
  int f = blockIdx.x*4 + wv;
  float4 fp = fpos[f];

  float c0v=3.5e38f, c1v=3.5e38f, c2v=3.5e38f;
  int   c0i=0x7fffffff, c1i=0x7fffffff, c2i=0x7fffffff;
  for (int j=lane; j<n_coarse; j+=64){
    float4 cp = cpos[j];
    float d2 = sqd(fp.w, cp.w, dot3(fp.x,fp.y,fp.z, cp.x,cp.y,cp.z));
    if (d2 < c2v || (d2 == c2v && j < c2i)){
      bool a0 = (d2 < c0v) || (d2 == c0v && j < c0i);
      bool a1 = (d2 < c1v) || (d2 == c1v && j < c1i);
      c2v = a1 ? c1v : d2;               c2i = a1 ? c1i : j;
      c1v = a0 ? c0v : (a1 ? d2 : c1v);  c1i = a0 ? c0i : (a1 ? j : c1i);
      c0v = a0 ? d2 : c0v;               c0i = a0 ? j  : c0i;
    }
  }
  float nnd[3]; int nni[3];
  #pragma unroll
  for (int r=0;r<3;r++){
    float v = c0v; int idx = c0i;
    #pragma unroll
    for (int s=1;s<64;s<<=1){
      float ov = __shfl_xor(v, s);
      int   oi = __shfl_xor(idx, s);
      bool tk = (ov < v) || (ov == v && oi < idx);
      v = tk ? ov : v; idx = tk ? oi : idx;
    }
    nnd[r] = v; nni[r] = idx;
    if (c0v == v && c0i == idx){
      c0v=c1v; c0i=c1i; c1v=c2v; c1i=c2i; c2v=3.5e38f; c2i=0x7fffffff;
    }
  }
  float w0 = fdiv_(1.0f, fmaxf(nnd[0], 1e-16f));
  float w1 = fdiv_(1.0f, fmaxf(nnd[1], 1e-16f));
  float w2 = fdiv_(1.0f, fmaxf(nnd[2], 1e-16f));
  float ws = fadd_(fadd_(w0,w1),w2);
  w0 = fdiv_(w0,ws); w1 = fdiv_(w1,ws); w2 = fdiv_(w2,ws);

  float hv = 0.0f;
  if (lane < 16){
    int c = lane;
    float x0 = Fc[(size_t)nni[0]*16 + c];
    float x1 = Fc[(size_t)nni[1]*16 + c];
    float x2 = Fc[(size_t)nni[2]*16 + c];
    hv = fadd_(fadd_(fmul_(w0,x0), fmul_(w1,x1)), fmul_(w2,x2));
  } else if (lane < 32){
    hv = Fs[(size_t)f*16 + (lane-16)];
  }
  int o1 = lane & 31;
  float acc = fmul_(__shfl(hv, 0), sW0[o1]);
  #pragma unroll
  for (int k=1;k<32;k++) acc = fmaf(__shfl(hv, k), sW0[k*32+o1], acc);
  float g1 = fmaxf(fadd_(acc, sb0[o1]), 0.0f);
  int o2 = lane & 15;
  float a2 = fmul_(__shfl(g1, 0), sW1[o2]);
  #pragma unroll
  for (int k=1;k<32;k++) a2 = fmaf(__shfl(g1, k), sW1[k*16+o2], a2);
  float g2 = fmaxf(fadd_(a2, sb1[o2]), 0.0f);

  if (!final_){
    if (lane < 16) outp[(size_t)f*16 + lane] = g2;
  } else {
    float a3 = fmul_(__shfl(g2, 0), sLW0[o2]);
    #pragma unroll
    for (int k=1;k<16;k++) a3 = fmaf(__shfl(g2, k), sLW0[k*16+o2], a3);
    float q = fmaxf(fadd_(a3, sLb0[o2]), 0.0f);
    int o3 = lane & 1;
    float a4 = fmul_(__shfl(q, 0), sLW1[o3]);
    #pragma unroll
    for (int k=1;k<16;k++) a4 = fmaf(__shfl(q, k), sLW1[k*2+o3], a4);
    a4 = fadd_(a4, sLb1[o3]);
    if (lane < 2) outp[(size_t)f*2 + lane] = a4;
  }
}

// ---------------------------------------------------------------------------
extern "C" void kernel_launch(void* const* d_in, const int* in_sizes, int n_in,
                              void* d_out, int out_size, void* d_ws, size_t ws_size,
                              hipStream_t stream) {
  (void)in_sizes; (void)n_in; (void)out_size; (void)ws_size;
  const float* x     = (const float*)d_in[0];
  const float* pos   = (const float*)d_in[1];
  const float* liW0  = (const float*)d_in[3];
  const float* lib0  = (const float*)d_in[4];
  const float* liW1  = (const float*)d_in[5];
  const float* lib1  = (const float*)d_in[6];
  const float* saW0  = (const float*)d_in[7];
  const float* sab0  = (const float*)d_in[8];
  const float* saW1  = (const float*)d_in[9];
  const float* sab1  = (const float*)d_in[10];
  const float* fpW0  = (const float*)d_in[11];
  const float* fpb0  = (const float*)d_in[12];
  const float* fpW1  = (const float*)d_in[13];
  const float* fpb1  = (const float*)d_in[14];
  const float* loW0  = (const float*)d_in[15];
  const float* lob0  = (const float*)d_in[16];
  const float* loW1  = (const float*)d_in[17];
  const float* lob1  = (const float*)d_in[18];
  float* out = (float*)d_out;

  char* ws = (char*)d_ws;
  size_t off = 0;
  auto alloc = [&](size_t bytes)->void* {
    void* p = ws + off;
    off += (bytes + 255) & ~(size_t)255;
    return p;
  };
  float4* P0 = (float4*)alloc(16384u*16);
  float4* P1 = (float4*)alloc(8192u*16);
  float4* P2 = (float4*)alloc(4096u*16);
  float4* P3 = (float4*)alloc(2048u*16);
  float*  F0 = (float*)alloc(16384u*16*4);
  float*  F1 = (float*)alloc(8192u*16*4);
  float*  F2 = (float*)alloc(4096u*16*4);
  float*  F3 = (float*)alloc(2048u*16*4);
  float*  G2 = (float*)alloc(4096u*16*4);
  float*  G1 = (float*)alloc(8192u*16*4);
  float4* S0 = (float4*)alloc(16384u*16);
  float4* S1 = (float4*)alloc(8192u*16);
  float4* S2 = (float4*)alloc(4096u*16);
  int*    R0 = (int*)alloc(256);

  k_prep<<<64,256,0,stream>>>(x,pos, liW0,lib0,liW1,lib1, P0,F0, 16384);

  // SA path (sort -> FPS -> group+conv per level)
  k_sort<<<1,1024,0,stream>>>(P0, S0, R0+0, 16384);
  k_fps2<<<1,256,0,stream>>>(S0, R0+0, P1, 16384, 8192);
  k_sa<<<2048,256,0,stream>>>(P0,16384, P1, F0, saW0,      sab0,    saW1,      sab1,    F1);
  k_sort<<<1,1024,0,stream>>>(P1, S1, R0+1, 8192);
  k_fps2<<<1,256,0,stream>>>(S1, R0+1, P2, 8192, 4096);
  k_sa<<<1024,256,0,stream>>>(P1, 8192, P2, F1, saW0+361,  sab0+19, saW1+304,  sab1+16, F2);
  k_sort<<<1,1024,0,stream>>>(P2, S2, R0+2, 4096);
  k_fps2<<<1,256,0,stream>>>(S2, R0+2, P3, 4096, 2048);
  k_sa<<< 512,256,0,stream>>>(P2, 4096, P3, F2, saW0+722,  sab0+38, saW1+608,  sab1+32, F3);

  // FP path
  k_fp<<<1024,256,0,stream>>>(P2, P3,2048, F3, F2,
      fpW0+2048, fpb0+64, fpW1+1024, fpb1+32,
      loW0,lob0,loW1,lob1, G2, 0);
  k_fp<<<2048,256,0,stream>>>(P1, P2,4096, G2, F1,
      fpW0+1024, fpb0+32, fpW1+512,  fpb1+16,
      loW0,lob0,loW1,lob1, G1, 0);
  k_fp<<<4096,256,0,stream>>>(P0, P1,8192, G1, F0,
      fpW0,      fpb0,    fpW1,      fpb1,
      loW0,lob0,loW1,lob1, out, 1);
}

// Round 3
// 26519.659 us; speedup vs baseline: 1.8306x; 1.8306x over previous
//
#include <hip/hip_runtime.h>
#include <stdint.h>

// ---------------------------------------------------------------------------
// PointNet++ forward, MI355X. Round 3: thread-parallel pruned FPS.
//   - k_sort: Morton counting sort (locality for pruning).
//   - k_fps3: 1024 threads; thread owns P contiguous sorted points in
//     registers with a private bbox skip test (no serialization). Cached
//     top-2 champions at thread and wave level; single-pass DPP pair-merge
//     top-2 reduces; one barrier/round; exact double-accept.
//   - prep/SA/FP unchanged (validated rounds 1-2).
// All reference-sensitive math uses explicit RN intrinsics (no contraction).
// ---------------------------------------------------------------------------

#define DEV static __device__ __forceinline__

DEV float fadd_(float a, float b){ return __fadd_rn(a,b); }
DEV float fsub_(float a, float b){ return __fsub_rn(a,b); }
DEV float fmul_(float a, float b){ return __fmul_rn(a,b); }
DEV float fdiv_(float a, float b){ return __fdiv_rn(a,b); }

DEV float dot3(float ax,float ay,float az,float bx,float by,float bz){
  return fmaf(az,bz, fmaf(ay,by, __fmul_rn(ax,bx)));
}
DEV float sqd(float na, float nb, float d){
  float t = __fadd_rn(na, nb);
  float u = __fmul_rn(2.0f, d);
  return fmaxf(__fsub_rn(t, u), 0.0f);
}

// conservative point-to-bbox squared distance (RN; margin applied by caller)
DEV float bbd2(float sx,float sy,float sz,
               float lx,float ly,float lz,float hx,float hy,float hz){
  float dx = fmaxf(fmaxf(fsub_(lx,sx), fsub_(sx,hx)), 0.0f);
  float dy = fmaxf(fmaxf(fsub_(ly,sy), fsub_(sy,hy)), 0.0f);
  float dz = fmaxf(fmaxf(fsub_(lz,sz), fsub_(sz,hz)), 0.0f);
  return fadd_(fadd_(fmul_(dx,dx),fmul_(dy,dy)),fmul_(dz,dz));
}

// ---------------- DPP top-2 (pair-merge) reduce ----------------------------
// old=0 everywhere: lanes that receive no data merge (0,0) = identity, so
// a lane can never self-merge (which would corrupt a top-2 pair).

#define DPP0(src, ctrl, rm, bc) \
  __builtin_amdgcn_update_dpp(0, (int)(src), (ctrl), (rm), 0xf, (bc))

#define DPP64(dst, src, ctrl, rm, bc) { \
  uint32_t lo_ = (uint32_t)DPP0((uint32_t)(src), ctrl, rm, bc); \
  uint32_t hi_ = (uint32_t)DPP0((uint32_t)((src)>>32), ctrl, rm, bc); \
  (dst) = (((unsigned long long)hi_)<<32) | lo_; }

// merge sorted pairs (A1>=A2) with incoming (b1>=b2):
// new1 = max(A1,b1); new2 = max(min(A1,b1), max(A2,b2))
#define MERGE2(A1, A2, ctrl, rm, bc) { \
  unsigned long long b1_, b2_, mn_, mx_; \
  DPP64(b1_, A1, ctrl, rm, bc); \
  DPP64(b2_, A2, ctrl, rm, bc); \
  mn_ = (A1) < b1_ ? (A1) : b1_; \
  mx_ = (A2) > b2_ ? (A2) : b2_; \
  (A1) = (A1) > b1_ ? (A1) : b1_; \
  (A2) = mn_ > mx_ ? mn_ : mx_; }

DEV unsigned long long rdlane64(unsigned long long v, int l){
  uint32_t lo=(uint32_t)__builtin_amdgcn_readlane((int)(uint32_t)v, l);
  uint32_t hi=(uint32_t)__builtin_amdgcn_readlane((int)(uint32_t)(v>>32), l);
  return (((unsigned long long)hi)<<32)|lo;
}

DEV void wtop2(unsigned long long &A1, unsigned long long &A2){  // 64 lanes
  MERGE2(A1,A2,0x111,0xf,true)
  MERGE2(A1,A2,0x112,0xf,true)
  MERGE2(A1,A2,0x114,0xf,true)
  MERGE2(A1,A2,0x118,0xf,true)
  MERGE2(A1,A2,0x142,0xa,false)   // row_bcast15 -> rows 1,3
  MERGE2(A1,A2,0x143,0xc,false)   // row_bcast31 -> rows 2,3
  A1 = rdlane64(A1,63); A2 = rdlane64(A2,63);
}
DEV void htop2(unsigned long long &A1, unsigned long long &A2){  // lanes 0..31
  MERGE2(A1,A2,0x111,0xf,true)
  MERGE2(A1,A2,0x112,0xf,true)
  MERGE2(A1,A2,0x114,0xf,true)
  MERGE2(A1,A2,0x118,0xf,true)
  MERGE2(A1,A2,0x142,0xa,false)
  A1 = rdlane64(A1,31); A2 = rdlane64(A2,31);
}

// ---------------------------------------------------------------------------
// prep: pos -> float4(x,y,z,|p|^2)  and  h0 = lin_in MLP(x)
// ---------------------------------------------------------------------------
__global__ __launch_bounds__(256) void k_prep(
    const float* __restrict__ x, const float* __restrict__ pos,
    const float* __restrict__ W0, const float* __restrict__ b0,
    const float* __restrict__ W1, const float* __restrict__ b1,
    float4* __restrict__ pos4, float* __restrict__ h_out, int n)
{
  __shared__ float sW0[256], sb0[16], sW1[256], sb1[16];
  int tid = threadIdx.x;
  sW0[tid] = W0[tid];
  sW1[tid] = W1[tid];
  if (tid < 16){ sb0[tid] = b0[tid]; sb1[tid] = b1[tid]; }
  __syncthreads();
  int p = blockIdx.x*256 + tid;
  if (p >= n) return;

  float px = pos[3*p], py = pos[3*p+1], pz = pos[3*p+2];
  float nrm = fadd_(fadd_(fmul_(px,px), fmul_(py,py)), fmul_(pz,pz));
  pos4[p] = make_float4(px,py,pz,nrm);

  const float4* xr = (const float4*)(x + (size_t)p*16);
  float4 v0 = xr[0], v1 = xr[1], v2 = xr[2], v3 = xr[3];
  float xin[16] = {v0.x,v0.y,v0.z,v0.w, v1.x,v1.y,v1.z,v1.w,
                   v2.x,v2.y,v2.z,v2.w, v3.x,v3.y,v3.z,v3.w};
  float h1[16];
  #pragma unroll
  for (int o=0;o<16;o++){
    float acc = fmul_(xin[0], sW0[o]);
    #pragma unroll
    for (int k=1;k<16;k++) acc = fmaf(xin[k], sW0[k*16+o], acc);
    h1[o] = fmaxf(fadd_(acc, sb0[o]), 0.0f);
  }
  float h2[16];
  #pragma unroll
  for (int o=0;o<16;o++){
    float acc = fmul_(h1[0], sW1[o]);
    #pragma unroll
    for (int k=1;k<16;k++) acc = fmaf(h1[k], sW1[k*16+o], acc);
    h2[o] = fmaxf(fadd_(acc, sb1[o]), 0.0f);
  }
  float4* hw = (float4*)(h_out + (size_t)p*16);
  hw[0] = make_float4(h2[0], h2[1], h2[2], h2[3]);
  hw[1] = make_float4(h2[4], h2[5], h2[6], h2[7]);
  hw[2] = make_float4(h2[8], h2[9], h2[10],h2[11]);
  hw[3] = make_float4(h2[12],h2[13],h2[14],h2[15]);
}

// ---------------------------------------------------------------------------
// k_sort: Morton counting sort (16^3 cells). Output w = bits(natural index).
// ---------------------------------------------------------------------------
DEV uint32_t expand4(uint32_t v){
  return (v&1u) | ((v&2u)<<2) | ((v&4u)<<4) | ((v&8u)<<6);
}
DEV int cellc(float v){
  int c = (int)(v*0.5f);
  return c < 0 ? 0 : (c > 15 ? 15 : c);
}
DEV uint32_t mkey(float4 p){
  return expand4((uint32_t)cellc(p.x))
       | (expand4((uint32_t)cellc(p.y))<<1)
       | (expand4((uint32_t)cellc(p.z))<<2);
}

__global__ __launch_bounds__(1024) void k_sort(
  const float4* __restrict__ nat, float4* __restrict__ srt,
  int* __restrict__ rank0, int n)
{
  __shared__ uint32_t hist[4096];
  __shared__ uint32_t gsum[1024];
  int tid = threadIdx.x;
  for (int i=tid;i<4096;i+=1024) hist[i]=0u;
  __syncthreads();
  for (int i=tid;i<n;i+=1024){
    float4 p = nat[i];
    atomicAdd(&hist[mkey(p)], 1u);
  }
  __syncthreads();
  uint32_t h0=hist[4*tid],h1=hist[4*tid+1],h2=hist[4*tid+2],h3=hist[4*tid+3];
  gsum[tid] = h0+h1+h2+h3;
  __syncthreads();
  for (int off=1; off<1024; off<<=1){
    uint32_t v = gsum[tid];
    uint32_t a = (tid>=off)? gsum[tid-off] : 0u;
    __syncthreads();
    gsum[tid] = v + a;
    __syncthreads();
  }
  uint32_t excl = (tid>0)? gsum[tid-1] : 0u;
  hist[4*tid]   = excl;
  hist[4*tid+1] = excl + h0;
  hist[4*tid+2] = excl + h0 + h1;
  hist[4*tid+3] = excl + h0 + h1 + h2;
  __syncthreads();
  for (int i=tid;i<n;i+=1024){
    float4 p = nat[i];
    uint32_t r = atomicAdd(&hist[mkey(p)], 1u);
    srt[r] = make_float4(p.x, p.y, p.z, __uint_as_float((uint32_t)i));
    if (i==0) *rank0 = (int)r;
  }
}

// ---------------------------------------------------------------------------
// k_fps3: thread-parallel pruned FPS, exact replication of the reference.
// 1024 threads; thread t owns points [t*P, (t+1)*P) of the sorted array in
// registers. Key = (mind_bits<<32) | ((0x3FFF-natidx)<<16) | sortedpos:
// u64 max == (mind desc, natidx asc). Cached top-2 at thread + wave level;
// double-accept when provably exact.
// ---------------------------------------------------------------------------
template<int P>
__global__ __launch_bounds__(1024) void k_fps3(
    const float4* __restrict__ sp4,   // sorted points, w = bits(natidx)
    const int* __restrict__ rank0p,
    float4* __restrict__ samp,        // selection-order output, w = |p|^2
    int m)
{
  __shared__ unsigned long long xch[2][32];
  const int t = threadIdx.x;
  const int lane = t & 63;
  const int w = t >> 6;

  float px[P], py[P], pz[P];
  uint32_t kh[P], kl[P];
  float blox,bloy,bloz,bhix,bhiy,bhiz;
  #pragma unroll
  for (int k=0;k<P;k++){
    float4 p = sp4[t*P+k];
    px[k]=p.x; py[k]=p.y; pz[k]=p.z;
    kh[k] = 0x7f800000u;                       // mind = +inf
    uint32_t nat = __float_as_uint(p.w);
    kl[k] = ((0x3FFFu - nat)<<16) | (uint32_t)(t*P+k);
    if (k==0){ blox=bhix=p.x; bloy=bhiy=p.y; bloz=bhiz=p.z; }
    else {
      blox=fminf(blox,p.x); bhix=fmaxf(bhix,p.x);
      bloy=fminf(bloy,p.y); bhiy=fmaxf(bhiy,p.y);
      bloz=fminf(bloz,p.z); bhiz=fmaxf(bhiz,p.z);
    }
  }

  float c1x,c1y,c1z, c2x=0.f,c2y=0.f,c2z=0.f;
  {
    int r0 = *rank0p;
    float4 s0 = sp4[r0];
    c1x=s0.x; c1y=s0.y; c1z=s0.z;
    if (t==0){
      float nr = fadd_(fadd_(fmul_(s0.x,s0.x),fmul_(s0.y,s0.y)),fmul_(s0.z,s0.z));
      samp[0] = make_float4(s0.x,s0.y,s0.z,nr);
    }
  }

  // cached champions; tc1 hi=inf forces round-1 update for every thread
  unsigned long long tc1 = ((unsigned long long)0x7f800000u)<<32, tc2 = 0ull;
  unsigned long long wt1 = 0ull, wt2 = 0ull;
  int u2 = 0, sel = 1, round = 0;

  while (true){
    // ---- thread-local skip test ------------------------------------------
    bool updp;
    {
      float cv = __uint_as_float((uint32_t)(tc1>>32));  // thread max mind
      float dm = bbd2(c1x,c1y,c1z, blox,bloy,bloz,bhix,bhiy,bhiz);
      if (u2){
        float dd = bbd2(c2x,c2y,c2z, blox,bloy,bloz,bhix,bhiy,bhiz);
        dm = fminf(dm, dd);
      }
      updp = (fmul_(dm, 0.99999f) < cv);
    }
    // ---- update + wave reduce only where needed --------------------------
    if (__ballot(updp) != 0ull){
      if (updp){
        tc1 = 0ull; tc2 = 0ull;
        if (u2){
          #pragma unroll
          for (int k=0;k<P;k++){
            float dx=fsub_(px[k],c1x), dy=fsub_(py[k],c1y), dz=fsub_(pz[k],c1z);
            float da = fadd_(fadd_(fmul_(dx,dx),fmul_(dy,dy)),fmul_(dz,dz));
            float ex=fsub_(px[k],c2x), ey=fsub_(py[k],c2y), ez=fsub_(pz[k],c2z);
            float db = fadd_(fadd_(fmul_(ex,ex),fmul_(ey,ey)),fmul_(ez,ez));
            float nm = fminf(__uint_as_float(kh[k]), fminf(da,db));
            kh[k] = __float_as_uint(nm);
            unsigned long long key = (((unsigned long long)kh[k])<<32) | kl[k];
            bool g1 = key > tc1;
            unsigned long long nt2 = g1 ? tc1 : (key > tc2 ? key : tc2);
            tc1 = g1 ? key : tc1;
            tc2 = nt2;
          }
        } else {
          #pragma unroll
          for (int k=0;k<P;k++){
            float dx=fsub_(px[k],c1x), dy=fsub_(py[k],c1y), dz=fsub_(pz[k],c1z);
            float da = fadd_(fadd_(fmul_(dx,dx),fmul_(dy,dy)),fmul_(dz,dz));
            float nm = fminf(__uint_as_float(kh[k]), da);
            kh[k] = __float_as_uint(nm);
            unsigned long long key = (((unsigned long long)kh[k])<<32) | kl[k];
            bool g1 = key > tc1;
            unsigned long long nt2 = g1 ? tc1 : (key > tc2 ? key : tc2);
            tc1 = g1 ? key : tc1;
            tc2 = nt2;
          }
        }
      }
      unsigned long long a1 = tc1, a2 = tc2;
      wtop2(a1, a2);
      wt1 = a1; wt2 = a2;
    }
    // ---- cross-wave top-2 (parity LDS, one barrier) ----------------------
    int par = round & 1;
    if (lane==0){ xch[par][2*w] = wt1; xch[par][2*w+1] = wt2; }
    __syncthreads();
    unsigned long long a1 = (lane<32) ? xch[par][lane] : 0ull;
    unsigned long long a2 = 0ull;
    htop2(a1, a2);
    int   sp1 = (int)(a1 & 0xFFFFu);
    int   sp2 = (int)(a2 & 0xFFFFu);
    float v2  = __uint_as_float((uint32_t)(a2>>32));
    float4 P1v = sp4[sp1];
    float4 P2v = sp4[sp2];
    // ---- exact double-accept ---------------------------------------------
    float qx=fsub_(P2v.x,P1v.x), qy=fsub_(P2v.y,P1v.y), qz=fsub_(P2v.z,P1v.z);
    float q  = fadd_(fadd_(fmul_(qx,qx),fmul_(qy,qy)),fmul_(qz,qz));
    bool acc2 = (sel+1 < m) && (q >= v2);
    if (t==0){
      float nr = fadd_(fadd_(fmul_(P1v.x,P1v.x),fmul_(P1v.y,P1v.y)),fmul_(P1v.z,P1v.z));
      samp[sel] = make_float4(P1v.x,P1v.y,P1v.z,nr);
    }
    if (acc2 && t==1){
      float nr = fadd_(fadd_(fmul_(P2v.x,P2v.x),fmul_(P2v.y,P2v.y)),fmul_(P2v.z,P2v.z));
      samp[sel+1] = make_float4(P2v.x,P2v.y,P2v.z,nr);
    }
    sel += acc2 ? 2 : 1;
    round++;
    if (sel >= m) break;
    c1x=P1v.x; c1y=P1v.y; c1z=P1v.z;
    u2 = acc2 ? 1 : 0;
    if (acc2){ c2x=P2v.x; c2y=P2v.y; c2z=P2v.z; }
  }
}

// ---------------------------------------------------------------------------
// SA: wave per target (unchanged)
// ---------------------------------------------------------------------------
#define SA_CAP 96

__global__ __launch_bounds__(256) void k_sa(
  const float4* __restrict__ spos, int n_src,
  const float4* __restrict__ tpos,
  const float*  __restrict__ F,
  const float* __restrict__ W0, const float* __restrict__ b0,
  const float* __restrict__ W1, const float* __restrict__ b1,
  float* __restrict__ Fout)
{
  __shared__ float sW0[361], sb0[19], sW1[304], sb1[16];
  __shared__ int   nidx[4][SA_CAP];
  __shared__ float nd2[4][SA_CAP];
  int tid = threadIdx.x;
  for (int i=tid;i<361;i+=256) sW0[i]=W0[i];
  for (int i=tid;i<304;i+=256) sW1[i]=W1[i];
  if (tid<19) sb0[tid]=b0[tid];
  if (tid<16) sb1[tid]=b1[tid];
  __syncthreads();

  int wv = tid >> 6, lane = tid & 63;
  int tg = blockIdx.x*4 + wv;
  float4 tp = tpos[tg];

  int cnt = 0;
  for (int base=0; base<n_src; base+=64){
    int j = base + lane;
    float4 sp = spos[j];
    float d2 = sqd(tp.w, sp.w, dot3(tp.x,tp.y,tp.z, sp.x,sp.y,sp.z));
    bool in = (d2 <= 4.0f);
    unsigned long long mk = __ballot(in);
    int pos = cnt + __popcll(mk & ((1ull<<lane)-1ull));
    if (in && pos < SA_CAP){ nidx[wv][pos]=j; nd2[wv][pos]=d2; }
    cnt += __popcll(mk);
  }
  if (cnt > SA_CAP) cnt = SA_CAP;

  if (cnt > 32){
    uint64_t tk0=0, tk1=0;
    for (int r=0;r<32;r++){
      float bvv = 3.5e38f; int bii = 0x7fffffff; int be = 0;
      for (int e=0;e<cnt;e++){
        bool done = (e<64) ? ((tk0>>e)&1ull) : ((tk1>>(e-64))&1ull);
        if (done) continue;
        float dv = nd2[wv][e]; int di = nidx[wv][e];
        if (dv < bvv || (dv == bvv && di < bii)){ bvv=dv; bii=di; be=e; }
      }
      if (be < 64) tk0 |= (1ull<<be); else tk1 |= (1ull<<(be-64));
    }
    int myi = 0; float myd = 0.0f;
    if (lane < 32){
      int seen = 0, sel = -1;
      for (int e=0;e<cnt && sel<0;e++){
        bool s = (e<64) ? ((tk0>>e)&1ull) : ((tk1>>(e-64))&1ull);
        if (s){ if (seen == lane) sel = e; seen++; }
      }
      myi = nidx[wv][sel]; myd = nd2[wv][sel];
    }
    __builtin_amdgcn_wave_barrier();
    if (lane < 32){ nidx[wv][lane]=myi; nd2[wv][lane]=myd; }
    __builtin_amdgcn_wave_barrier();
    cnt = 32;
  }

  float in19[19];
  #pragma unroll
  for (int k=0;k<19;k++) in19[k] = 0.0f;
  if (lane < cnt){
    int j = nidx[wv][lane];
    const float4* fr = (const float4*)(F + (size_t)j*16);
    float4 a=fr[0], b=fr[1], c=fr[2], d=fr[3];
    in19[0]=a.x; in19[1]=a.y; in19[2]=a.z; in19[3]=a.w;
    in19[4]=b.x; in19[5]=b.y; in19[6]=b.z; in19[7]=b.w;
    in19[8]=c.x; in19[9]=c.y; in19[10]=c.z; in19[11]=c.w;
    in19[12]=d.x; in19[13]=d.y; in19[14]=d.z; in19[15]=d.w;
    float4 sp = spos[j];
    in19[16]=fsub_(sp.x,tp.x); in19[17]=fsub_(sp.y,tp.y); in19[18]=fsub_(sp.z,tp.z);
  }
  float h[19];
  #pragma unroll
  for (int o=0;o<19;o++){
    float acc = fmul_(in19[0], sW0[o]);
    #pragma unroll
    for (int k=1;k<19;k++) acc = fmaf(in19[k], sW0[k*19+o], acc);
    h[o] = fmaxf(fadd_(acc, sb0[o]), 0.0f);
  }
  float outv[16];
  #pragma unroll
  for (int o=0;o<16;o++){
    float acc = fmul_(h[0], sW1[o]);
    #pragma unroll
    for (int k=1;k<19;k++) acc = fmaf(h[k], sW1[k*16+o], acc);
    float v = fmaxf(fadd_(acc, sb1[o]), 0.0f);
    outv[o] = (lane < cnt) ? v : -1e30f;
  }
  #pragma unroll
  for (int o=0;o<16;o++){
    float v = outv[o];
    #pragma unroll
    for (int s=1;s<64;s<<=1) v = fmaxf(v, __shfl_xor(v, s));
    outv[o] = v;
  }
  if (lane == 0){
    float4* dst = (float4*)(Fout + (size_t)tg*16);
    dst[0] = make_float4(outv[0], outv[1], outv[2], outv[3]);
    dst[1] = make_float4(outv[4], outv[5], outv[6], outv[7]);
    dst[2] = make_float4(outv[8], outv[9], outv[10],outv[11]);
    dst[3] = make_float4(outv[12],outv[13],outv[14],outv[15]);
  }
}

// ---------------------------------------------------------------------------
// FP: wave per fine point (unchanged)
// ---------------------------------------------------------------------------
__global__ __launch_bounds__(256) void k_fp(
  const float4* __restrict__ fpos,
  const float4* __restrict__ cpos, int n_coarse,
  const float* __restrict__ Fc, const float* __restrict__ Fs,
  const float* __restrict__ W0, const float* __restrict__ b0,
  const float* __restrict__ W1, const float* __restrict__ b1,
  const float* __restrict__ loW0, const float* __restrict__ lob0,
  const float* __restrict__ loW1, const float* __restrict__ lob1,
  float* __restrict__ outp, int final_)
{
  __shared__ float sW0[1024], sb0[32], sW1[512], sb1[16];
  __shared__ float sLW0[256], sLb0[16], sLW1[32], sLb1[2];
  int tid = threadIdx.x;
  for (int i=tid;i<1024;i+=256) sW0[i]=W0[i];
  for (int i=tid;i<512;i+=256)  sW1[i]=W1[i];
  if (tid<32) sb0[tid]=b0[tid];
  if (tid<16) sb1[tid]=b1[tid];
  if (final_){
    sLW0[tid & 255] = loW0[tid & 255];
    if (tid<16) sLb0[tid]=lob0[tid];
    if (tid<32) sLW1[tid]=loW1[tid];
    if (tid<2)  sLb1[tid]=lob1[tid];
  }
  __syncthreads();

  int wv = tid >> 6, lane = tid & 63;
  int f = blockIdx.x*4 + wv;
  float4 fp = fpos[f];

  float c0v=3.5e38f, c1v=3.5e38f, c2v=3.5e38f;
  int   c0i=0x7fffffff, c1i=0x7fffffff, c2i=0x7fffffff;
  for (int j=lane; j<n_coarse; j+=64){
    float4 cp = cpos[j];
    float d2 = sqd(fp.w, cp.w, dot3(fp.x,fp.y,fp.z, cp.x,cp.y,cp.z));
    if (d2 < c2v || (d2 == c2v && j < c2i)){
      bool a0 = (d2 < c0v) || (d2 == c0v && j < c0i);
      bool a1 = (d2 < c1v) || (d2 == c1v && j < c1i);
      c2v = a1 ? c1v : d2;               c2i = a1 ? c1i : j;
      c1v = a0 ? c0v : (a1 ? d2 : c1v);  c1i = a0 ? c0i : (a1 ? j : c1i);
      c0v = a0 ? d2 : c0v;               c0i = a0 ? j  : c0i;
    }
  }
  float nnd[3]; int nni[3];
  #pragma unroll
  for (int r=0;r<3;r++){
    float v = c0v; int idx = c0i;
    #pragma unroll
    for (int s=1;s<64;s<<=1){
      float ov = __shfl_xor(v, s);
      int   oi = __shfl_xor(idx, s);
      bool tk = (ov < v) || (ov == v && oi < idx);
      v = tk ? ov : v; idx = tk ? oi : idx;
    }
    nnd[r] = v; nni[r] = idx;
    if (c0v == v && c0i == idx){
      c0v=c1v; c0i=c1i; c1v=c2v; c1i=c2i; c2v=3.5e38f; c2i=0x7fffffff;
    }
  }
  float w0 = fdiv_(1.0f, fmaxf(nnd[0], 1e-16f));
  float w1 = fdiv_(1.0f, fmaxf(nnd[1], 1e-16f));
  float w2 = fdiv_(1.0f, fmaxf(nnd[2], 1e-16f));
  float ws = fadd_(fadd_(w0,w1),w2);
  w0 = fdiv_(w0,ws); w1 = fdiv_(w1,ws); w2 = fdiv_(w2,ws);

  float hv = 0.0f;
  if (lane < 16){
    int c = lane;
    float x0 = Fc[(size_t)nni[0]*16 + c];
    float x1 = Fc[(size_t)nni[1]*16 + c];
    float x2 = Fc[(size_t)nni[2]*16 + c];
    hv = fadd_(fadd_(fmul_(w0,x0), fmul_(w1,x1)), fmul_(w2,x2));
  } else if (lane < 32){
    hv = Fs[(size_t)f*16 + (lane-16)];
  }
  int o1 = lane & 31;
  float acc = fmul_(__shfl(hv, 0), sW0[o1]);
  #pragma unroll
  for (int k=1;k<32;k++) acc = fmaf(__shfl(hv, k), sW0[k*32+o1], acc);
  float g1 = fmaxf(fadd_(acc, sb0[o1]), 0.0f);
  int o2 = lane & 15;
  float a2 = fmul_(__shfl(g1, 0), sW1[o2]);
  #pragma unroll
  for (int k=1;k<32;k++) a2 = fmaf(__shfl(g1, k), sW1[k*16+o2], a2);
  float g2 = fmaxf(fadd_(a2, sb1[o2]), 0.0f);

  if (!final_){
    if (lane < 16) outp[(size_t)f*16 + lane] = g2;
  } else {
    float a3 = fmul_(__shfl(g2, 0), sLW0[o2]);
    #pragma unroll
    for (int k=1;k<16;k++) a3 = fmaf(__shfl(g2, k), sLW0[k*16+o2], a3);
    float q = fmaxf(fadd_(a3, sLb0[o2]), 0.0f);
    int o3 = lane & 1;
    float a4 = fmul_(__shfl(q, 0), sLW1[o3]);
    #pragma unroll
    for (int k=1;k<16;k++) a4 = fmaf(__shfl(q, k), sLW1[k*2+o3], a4);
    a4 = fadd_(a4, sLb1[o3]);
    if (lane < 2) outp[(size_t)f*2 + lane] = a4;
  }
}

// ---------------------------------------------------------------------------
extern "C" void kernel_launch(void* const* d_in, const int* in_sizes, int n_in,
                              void* d_out, int out_size, void* d_ws, size_t ws_size,
                              hipStream_t stream) {
  (void)in_sizes; (void)n_in; (void)out_size; (void)ws_size;
  const float* x     = (const float*)d_in[0];
  const float* pos   = (const float*)d_in[1];
  const float* liW0  = (const float*)d_in[3];
  const float* lib0  = (const float*)d_in[4];
  const float* liW1  = (const float*)d_in[5];
  const float* lib1  = (const float*)d_in[6];
  const float* saW0  = (const float*)d_in[7];
  const float* sab0  = (const float*)d_in[8];
  const float* saW1  = (const float*)d_in[9];
  const float* sab1  = (const float*)d_in[10];
  const float* fpW0  = (const float*)d_in[11];
  const float* fpb0  = (const float*)d_in[12];
  const float* fpW1  = (const float*)d_in[13];
  const float* fpb1  = (const float*)d_in[14];
  const float* loW0  = (const float*)d_in[15];
  const float* lob0  = (const float*)d_in[16];
  const float* loW1  = (const float*)d_in[17];
  const float* lob1  = (const float*)d_in[18];
  float* out = (float*)d_out;

  char* ws = (char*)d_ws;
  size_t off = 0;
  auto alloc = [&](size_t bytes)->void* {
    void* p = ws + off;
    off += (bytes + 255) & ~(size_t)255;
    return p;
  };
  float4* P0 = (float4*)alloc(16384u*16);
  float4* P1 = (float4*)alloc(8192u*16);
  float4* P2 = (float4*)alloc(4096u*16);
  float4* P3 = (float4*)alloc(2048u*16);
  float*  F0 = (float*)alloc(16384u*16*4);
  float*  F1 = (float*)alloc(8192u*16*4);
  float*  F2 = (float*)alloc(4096u*16*4);
  float*  F3 = (float*)alloc(2048u*16*4);
  float*  G2 = (float*)alloc(4096u*16*4);
  float*  G1 = (float*)alloc(8192u*16*4);
  float4* S0 = (float4*)alloc(16384u*16);
  float4* S1 = (float4*)alloc(8192u*16);
  float4* S2 = (float4*)alloc(4096u*16);
  int*    R0 = (int*)alloc(256);

  k_prep<<<64,256,0,stream>>>(x,pos, liW0,lib0,liW1,lib1, P0,F0, 16384);

  // SA path (sort -> FPS -> group+conv per level)
  k_sort<<<1,1024,0,stream>>>(P0, S0, R0+0, 16384);
  k_fps3<16><<<1,1024,0,stream>>>(S0, R0+0, P1, 8192);
  k_sa<<<2048,256,0,stream>>>(P0,16384, P1, F0, saW0,      sab0,    saW1,      sab1,    F1);
  k_sort<<<1,1024,0,stream>>>(P1, S1, R0+1, 8192);
  k_fps3<8><<<1,1024,0,stream>>>(S1, R0+1, P2, 4096);
  k_sa<<<1024,256,0,stream>>>(P1, 8192, P2, F1, saW0+361,  sab0+19, saW1+304,  sab1+16, F2);
  k_sort<<<1,1024,0,stream>>>(P2, S2, R0+2, 4096);
  k_fps3<4><<<1,1024,0,stream>>>(S2, R0+2, P3, 2048);
  k_sa<<< 512,256,0,stream>>>(P2, 4096, P3, F2, saW0+722,  sab0+38, saW1+608,  sab1+32, F3);

  // FP path
  k_fp<<<1024,256,0,stream>>>(P2, P3,2048, F3, F2,
      fpW0+2048, fpb0+64, fpW1+1024, fpb1+32,
      loW0,lob0,loW1,lob1, G2, 0);
  k_fp<<<2048,256,0,stream>>>(P1, P2,4096, G2, F1,
      fpW0+1024, fpb0+32, fpW1+512,  fpb1+16,
      loW0,lob0,loW1,lob1, G1, 0);
  k_fp<<<4096,256,0,stream>>>(P0, P1,8192, G1, F0,
      fpW0,      fpb0,    fpW1,      fpb1,
      loW0,lob0,loW1,lob1, out, 1);
}

// Round 4
// 20592.017 us; speedup vs baseline: 2.3575x; 1.2879x over previous
//
#include <hip/hip_runtime.h>
#include <stdint.h>

// ---------------------------------------------------------------------------
// PointNet++ forward, MI355X. Round 4: de-spilled FPS.
//   - mind lives in LDS (thread-private, transposed, conflict-free); coords +
//     static key-low live in registers (~110 VGPR, fits 128 cap @1024 thr).
//   - candidate coords broadcast through LDS (no dependent global loads on
//     the per-round critical path).
//   - same keys / DPP pair-merge top-2 / exact double-accept as round 3
//     (validated bit-identical); prep/sort/SA/FP unchanged.
// ---------------------------------------------------------------------------

#define DEV static __device__ __forceinline__

DEV float fadd_(float a, float b){ return __fadd_rn(a,b); }
DEV float fsub_(float a, float b){ return __fsub_rn(a,b); }
DEV float fmul_(float a, float b){ return __fmul_rn(a,b); }
DEV float fdiv_(float a, float b){ return __fdiv_rn(a,b); }

DEV float dot3(float ax,float ay,float az,float bx,float by,float bz){
  return fmaf(az,bz, fmaf(ay,by, __fmul_rn(ax,bx)));
}
DEV float sqd(float na, float nb, float d){
  float t = __fadd_rn(na, nb);
  float u = __fmul_rn(2.0f, d);
  return fmaxf(__fsub_rn(t, u), 0.0f);
}

// conservative point-to-bbox squared distance
DEV float bbd2(float sx,float sy,float sz,
               float lx,float ly,float lz,float hx,float hy,float hz){
  float dx = fmaxf(fmaxf(fsub_(lx,sx), fsub_(sx,hx)), 0.0f);
  float dy = fmaxf(fmaxf(fsub_(ly,sy), fsub_(sy,hy)), 0.0f);
  float dz = fmaxf(fmaxf(fsub_(lz,sz), fsub_(sz,hz)), 0.0f);
  return fadd_(fadd_(fmul_(dx,dx),fmul_(dy,dy)),fmul_(dz,dz));
}

// ---------------- DPP top-2 (pair-merge) reduce (validated round 3) --------
#define DPP0(src, ctrl, rm, bc) \
  __builtin_amdgcn_update_dpp(0, (int)(src), (ctrl), (rm), 0xf, (bc))

#define DPP64(dst, src, ctrl, rm, bc) { \
  uint32_t lo_ = (uint32_t)DPP0((uint32_t)(src), ctrl, rm, bc); \
  uint32_t hi_ = (uint32_t)DPP0((uint32_t)((src)>>32), ctrl, rm, bc); \
  (dst) = (((unsigned long long)hi_)<<32) | lo_; }

#define MERGE2(A1, A2, ctrl, rm, bc) { \
  unsigned long long b1_, b2_, mn_, mx_; \
  DPP64(b1_, A1, ctrl, rm, bc); \
  DPP64(b2_, A2, ctrl, rm, bc); \
  mn_ = (A1) < b1_ ? (A1) : b1_; \
  mx_ = (A2) > b2_ ? (A2) : b2_; \
  (A1) = (A1) > b1_ ? (A1) : b1_; \
  (A2) = mn_ > mx_ ? mn_ : mx_; }

DEV unsigned long long rdlane64(unsigned long long v, int l){
  uint32_t lo=(uint32_t)__builtin_amdgcn_readlane((int)(uint32_t)v, l);
  uint32_t hi=(uint32_t)__builtin_amdgcn_readlane((int)(uint32_t)(v>>32), l);
  return (((unsigned long long)hi)<<32)|lo;
}

DEV void wtop2(unsigned long long &A1, unsigned long long &A2){  // 64 lanes
  MERGE2(A1,A2,0x111,0xf,true)
  MERGE2(A1,A2,0x112,0xf,true)
  MERGE2(A1,A2,0x114,0xf,true)
  MERGE2(A1,A2,0x118,0xf,true)
  MERGE2(A1,A2,0x142,0xa,false)
  MERGE2(A1,A2,0x143,0xc,false)
  A1 = rdlane64(A1,63); A2 = rdlane64(A2,63);
}
DEV void htop2(unsigned long long &A1, unsigned long long &A2){  // lanes 0..31
  MERGE2(A1,A2,0x111,0xf,true)
  MERGE2(A1,A2,0x112,0xf,true)
  MERGE2(A1,A2,0x114,0xf,true)
  MERGE2(A1,A2,0x118,0xf,true)
  MERGE2(A1,A2,0x142,0xa,false)
  A1 = rdlane64(A1,31); A2 = rdlane64(A2,31);
}

// ---------------------------------------------------------------------------
// prep: pos -> float4(x,y,z,|p|^2)  and  h0 = lin_in MLP(x)
// ---------------------------------------------------------------------------
__global__ __launch_bounds__(256) void k_prep(
    const float* __restrict__ x, const float* __restrict__ pos,
    const float* __restrict__ W0, const float* __restrict__ b0,
    const float* __restrict__ W1, const float* __restrict__ b1,
    float4* __restrict__ pos4, float* __restrict__ h_out, int n)
{
  __shared__ float sW0[256], sb0[16], sW1[256], sb1[16];
  int tid = threadIdx.x;
  sW0[tid] = W0[tid];
  sW1[tid] = W1[tid];
  if (tid < 16){ sb0[tid] = b0[tid]; sb1[tid] = b1[tid]; }
  __syncthreads();
  int p = blockIdx.x*256 + tid;
  if (p >= n) return;

  float px = pos[3*p], py = pos[3*p+1], pz = pos[3*p+2];
  float nrm = fadd_(fadd_(fmul_(px,px), fmul_(py,py)), fmul_(pz,pz));
  pos4[p] = make_float4(px,py,pz,nrm);

  const float4* xr = (const float4*)(x + (size_t)p*16);
  float4 v0 = xr[0], v1 = xr[1], v2 = xr[2], v3 = xr[3];
  float xin[16] = {v0.x,v0.y,v0.z,v0.w, v1.x,v1.y,v1.z,v1.w,
                   v2.x,v2.y,v2.z,v2.w, v3.x,v3.y,v3.z,v3.w};
  float h1[16];
  #pragma unroll
  for (int o=0;o<16;o++){
    float acc = fmul_(xin[0], sW0[o]);
    #pragma unroll
    for (int k=1;k<16;k++) acc = fmaf(xin[k], sW0[k*16+o], acc);
    h1[o] = fmaxf(fadd_(acc, sb0[o]), 0.0f);
  }
  float h2[16];
  #pragma unroll
  for (int o=0;o<16;o++){
    float acc = fmul_(h1[0], sW1[o]);
    #pragma unroll
    for (int k=1;k<16;k++) acc = fmaf(h1[k], sW1[k*16+o], acc);
    h2[o] = fmaxf(fadd_(acc, sb1[o]), 0.0f);
  }
  float4* hw = (float4*)(h_out + (size_t)p*16);
  hw[0] = make_float4(h2[0], h2[1], h2[2], h2[3]);
  hw[1] = make_float4(h2[4], h2[5], h2[6], h2[7]);
  hw[2] = make_float4(h2[8], h2[9], h2[10],h2[11]);
  hw[3] = make_float4(h2[12],h2[13],h2[14],h2[15]);
}

// ---------------------------------------------------------------------------
// k_sort: Morton counting sort (16^3 cells). Output w = bits(natural index).
// ---------------------------------------------------------------------------
DEV uint32_t expand4(uint32_t v){
  return (v&1u) | ((v&2u)<<2) | ((v&4u)<<4) | ((v&8u)<<6);
}
DEV int cellc(float v){
  int c = (int)(v*0.5f);
  return c < 0 ? 0 : (c > 15 ? 15 : c);
}
DEV uint32_t mkey(float4 p){
  return expand4((uint32_t)cellc(p.x))
       | (expand4((uint32_t)cellc(p.y))<<1)
       | (expand4((uint32_t)cellc(p.z))<<2);
}

__global__ __launch_bounds__(1024) void k_sort(
  const float4* __restrict__ nat, float4* __restrict__ srt,
  int* __restrict__ rank0, int n)
{
  __shared__ uint32_t hist[4096];
  __shared__ uint32_t gsum[1024];
  int tid = threadIdx.x;
  for (int i=tid;i<4096;i+=1024) hist[i]=0u;
  __syncthreads();
  for (int i=tid;i<n;i+=1024){
    float4 p = nat[i];
    atomicAdd(&hist[mkey(p)], 1u);
  }
  __syncthreads();
  uint32_t h0=hist[4*tid],h1=hist[4*tid+1],h2=hist[4*tid+2],h3=hist[4*tid+3];
  gsum[tid] = h0+h1+h2+h3;
  __syncthreads();
  for (int off=1; off<1024; off<<=1){
    uint32_t v = gsum[tid];
    uint32_t a = (tid>=off)? gsum[tid-off] : 0u;
    __syncthreads();
    gsum[tid] = v + a;
    __syncthreads();
  }
  uint32_t excl = (tid>0)? gsum[tid-1] : 0u;
  hist[4*tid]   = excl;
  hist[4*tid+1] = excl + h0;
  hist[4*tid+2] = excl + h0 + h1;
  hist[4*tid+3] = excl + h0 + h1 + h2;
  __syncthreads();
  for (int i=tid;i<n;i+=1024){
    float4 p = nat[i];
    uint32_t r = atomicAdd(&hist[mkey(p)], 1u);
    srt[r] = make_float4(p.x, p.y, p.z, __uint_as_float((uint32_t)i));
    if (i==0) *rank0 = (int)r;
  }
}

// ---------------------------------------------------------------------------
// k_fps4: thread-parallel pruned FPS. 1024 threads, thread t owns points
// [t*P,(t+1)*P): coords + klo in REGISTERS, mind in LDS (transposed,
// thread-private, conflict-free). Key=(mind<<32)|((0x3FFF-nat)<<16)|spos.
// Candidate coords broadcast via stride-5 parity LDS slots. Exact
// double-accept. Bit-identical to rounds 1-3 selections.
// ---------------------------------------------------------------------------
template<int P>
__global__ __launch_bounds__(1024,4) void k_fps4(
    const float4* __restrict__ sp4,   // sorted points, w = bits(natidx)
    const int* __restrict__ rank0p,
    float4* __restrict__ samp,        // selection-order output, w = |p|^2
    int m)
{
  __shared__ float smind[P*1024];
  __shared__ uint32_t xch[2][32*5];   // [parity][slot*5 + {klo,khi,x,y,z}]
  const int t = threadIdx.x;
  const int lane = t & 63;
  const int w = t >> 6;

  float px[P], py[P], pz[P];
  uint32_t klo[P];
  float blox,bloy,bloz,bhix,bhiy,bhiz;
  #pragma unroll
  for (int k=0;k<P;k++){
    float4 p = sp4[t*P+k];
    px[k]=p.x; py[k]=p.y; pz[k]=p.z;
    uint32_t nat = __float_as_uint(p.w);
    klo[k] = ((0x3FFFu - nat)<<16) | (uint32_t)(t*P+k);
    smind[k*1024+t] = __builtin_inff();
    if (k==0){ blox=bhix=p.x; bloy=bhiy=p.y; bloz=bhiz=p.z; }
    else {
      blox=fminf(blox,p.x); bhix=fmaxf(bhix,p.x);
      bloy=fminf(bloy,p.y); bhiy=fmaxf(bhiy,p.y);
      bloz=fminf(bloz,p.z); bhiz=fmaxf(bhiz,p.z);
    }
  }

  float c1x,c1y,c1z, c2x=0.f,c2y=0.f,c2z=0.f;
  {
    int r0 = *rank0p;
    float4 s0 = sp4[r0];
    c1x=s0.x; c1y=s0.y; c1z=s0.z;
    if (t==0){
      float nr = fadd_(fadd_(fmul_(s0.x,s0.x),fmul_(s0.y,s0.y)),fmul_(s0.z,s0.z));
      samp[0] = make_float4(s0.x,s0.y,s0.z,nr);
    }
  }
  __syncthreads();

  // thread champions; hi=inf forces round-0 update for every thread
  unsigned long long tc1 = ((unsigned long long)0x7f800000u)<<32, tc2 = 0ull;
  // cached owner slots (valid after round 0)
  bool own1 = false, own2 = false;
  uint32_t c1lo=0,c1hi=0, c2lo=0,c2hi=0;
  float o1x=0,o1y=0,o1z=0, o2x=0,o2y=0,o2z=0;

  int u2 = 0, sel = 1, round = 0;

  while (true){
    // ---- thread-local skip test ------------------------------------------
    bool updp;
    {
      float cv = __uint_as_float((uint32_t)(tc1>>32));
      float dm = bbd2(c1x,c1y,c1z, blox,bloy,bloz,bhix,bhiy,bhiz);
      if (u2){
        float dd = bbd2(c2x,c2y,c2z, blox,bloy,bloz,bhix,bhiy,bhiz);
        dm = fminf(dm, dd);
      }
      updp = (fmul_(dm, 0.99999f) < cv);
    }
    // ---- update + wave reduce + owner refresh only where needed ----------
    if (__ballot(updp) != 0ull){
      if (updp){
        tc1 = 0ull; tc2 = 0ull;
        #pragma unroll
        for (int k=0;k<P;k++){
          float dx=fsub_(px[k],c1x), dy=fsub_(py[k],c1y), dz=fsub_(pz[k],c1z);
          float da = fadd_(fadd_(fmul_(dx,dx),fmul_(dy,dy)),fmul_(dz,dz));
          float nm = fminf(smind[k*1024+t], da);
          if (u2){
            float ex=fsub_(px[k],c2x), ey=fsub_(py[k],c2y), ez=fsub_(pz[k],c2z);
            float db = fadd_(fadd_(fmul_(ex,ex),fmul_(ey,ey)),fmul_(ez,ez));
            nm = fminf(nm, db);
          }
          smind[k*1024+t] = nm;
          unsigned long long key =
            (((unsigned long long)__float_as_uint(nm))<<32) | klo[k];
          bool g1 = key > tc1;
          unsigned long long nt2 = g1 ? tc1 : (key > tc2 ? key : tc2);
          tc1 = g1 ? key : tc1;
          tc2 = nt2;
        }
      }
      unsigned long long a1 = tc1, a2 = tc2;
      wtop2(a1, a2);
      // refresh owner caches (whole wave)
      own1 = (tc1 == a1);
      own2 = (tc1 == a2) || (tc2 == a2);
      int kk1 = (int)(a1 & (unsigned long long)(P-1));
      int kk2 = (int)(a2 & (unsigned long long)(P-1));
      float sx1=px[0], sy1=py[0], sz1=pz[0];
      float sx2=px[0], sy2=py[0], sz2=pz[0];
      #pragma unroll
      for (int j=1;j<P;j++){
        bool e1=(j==kk1), e2=(j==kk2);
        sx1=e1?px[j]:sx1; sy1=e1?py[j]:sy1; sz1=e1?pz[j]:sz1;
        sx2=e2?px[j]:sx2; sy2=e2?py[j]:sy2; sz2=e2?pz[j]:sz2;
      }
      c1lo=(uint32_t)a1; c1hi=(uint32_t)(a1>>32); o1x=sx1; o1y=sy1; o1z=sz1;
      c2lo=(uint32_t)a2; c2hi=(uint32_t)(a2>>32); o2x=sx2; o2y=sy2; o2z=sz2;
    }
    // ---- publish wave candidates (owners rewrite every round) ------------
    int par = round & 1;
    if (own1){
      int b = (w*2)*5;
      xch[par][b]=c1lo; xch[par][b+1]=c1hi;
      xch[par][b+2]=__float_as_uint(o1x);
      xch[par][b+3]=__float_as_uint(o1y);
      xch[par][b+4]=__float_as_uint(o1z);
    }
    if (own2){
      int b = (w*2+1)*5;
      xch[par][b]=c2lo; xch[par][b+1]=c2hi;
      xch[par][b+2]=__float_as_uint(o2x);
      xch[par][b+3]=__float_as_uint(o2y);
      xch[par][b+4]=__float_as_uint(o2z);
    }
    __syncthreads();
    // ---- global top-2 over 32 slots (all waves redundantly) --------------
    unsigned long long cnd = 0ull;
    if (lane < 32){
      uint32_t lo = xch[par][lane*5], hi = xch[par][lane*5+1];
      cnd = (((unsigned long long)hi)<<32) | lo;
    }
    unsigned long long a1 = cnd, a2 = 0ull;
    htop2(a1, a2);
    unsigned long long b1 = __ballot(lane<32 && cnd==a1);
    unsigned long long b2 = __ballot(lane<32 && cnd==a2);
    int s1 = __ffsll(b1)-1;
    int s2 = __ffsll(b2)-1;
    float p1x=__uint_as_float(xch[par][s1*5+2]);
    float p1y=__uint_as_float(xch[par][s1*5+3]);
    float p1z=__uint_as_float(xch[par][s1*5+4]);
    float p2x=__uint_as_float(xch[par][s2*5+2]);
    float p2y=__uint_as_float(xch[par][s2*5+3]);
    float p2z=__uint_as_float(xch[par][s2*5+4]);
    float v2 = __uint_as_float((uint32_t)(a2>>32));
    // ---- exact double-accept ---------------------------------------------
    float qx=fsub_(p2x,p1x), qy=fsub_(p2y,p1y), qz=fsub_(p2z,p1z);
    float q  = fadd_(fadd_(fmul_(qx,qx),fmul_(qy,qy)),fmul_(qz,qz));
    bool acc2 = (sel+1 < m) && (q >= v2);
    if (t==0){
      float nr = fadd_(fadd_(fmul_(p1x,p1x),fmul_(p1y,p1y)),fmul_(p1z,p1z));
      samp[sel] = make_float4(p1x,p1y,p1z,nr);
    }
    if (acc2 && t==1){
      float nr = fadd_(fadd_(fmul_(p2x,p2x),fmul_(p2y,p2y)),fmul_(p2z,p2z));
      samp[sel+1] = make_float4(p2x,p2y,p2z,nr);
    }
    sel += acc2 ? 2 : 1;
    round++;
    if (sel >= m) break;
    c1x=p1x; c1y=p1y; c1z=p1z;
    u2 = acc2 ? 1 : 0;
    if (acc2){ c2x=p2x; c2y=p2y; c2z=p2z; }
  }
}

// ---------------------------------------------------------------------------
// SA: wave per target (unchanged)
// ---------------------------------------------------------------------------
#define SA_CAP 96

__global__ __launch_bounds__(256) void k_sa(
  const float4* __restrict__ spos, int n_src,
  const float4* __restrict__ tpos,
  const float*  __restrict__ F,
  const float* __restrict__ W0, const float* __restrict__ b0,
  const float* __restrict__ W1, const float* __restrict__ b1,
  float* __restrict__ Fout)
{
  __shared__ float sW0[361], sb0[19], sW1[304], sb1[16];
  __shared__ int   nidx[4][SA_CAP];
  __shared__ float nd2[4][SA_CAP];
  int tid = threadIdx.x;
  for (int i=tid;i<361;i+=256) sW0[i]=W0[i];
  for (int i=tid;i<304;i+=256) sW1[i]=W1[i];
  if (tid<19) sb0[tid]=b0[tid];
  if (tid<16) sb1[tid]=b1[tid];
  __syncthreads();

  int wv = tid >> 6, lane = tid & 63;
  int tg = blockIdx.x*4 + wv;
  float4 tp = tpos[tg];

  int cnt = 0;
  for (int base=0; base<n_src; base+=64){
    int j = base + lane;
    float4 sp = spos[j];
    float d2 = sqd(tp.w, sp.w, dot3(tp.x,tp.y,tp.z, sp.x,sp.y,sp.z));
    bool in = (d2 <= 4.0f);
    unsigned long long mk = __ballot(in);
    int pos = cnt + __popcll(mk & ((1ull<<lane)-1ull));
    if (in && pos < SA_CAP){ nidx[wv][pos]=j; nd2[wv][pos]=d2; }
    cnt += __popcll(mk);
  }
  if (cnt > SA_CAP) cnt = SA_CAP;

  if (cnt > 32){
    uint64_t tk0=0, tk1=0;
    for (int r=0;r<32;r++){
      float bvv = 3.5e38f; int bii = 0x7fffffff; int be = 0;
      for (int e=0;e<cnt;e++){
        bool done = (e<64) ? ((tk0>>e)&1ull) : ((tk1>>(e-64))&1ull);
        if (done) continue;
        float dv = nd2[wv][e]; int di = nidx[wv][e];
        if (dv < bvv || (dv == bvv && di < bii)){ bvv=dv; bii=di; be=e; }
      }
      if (be < 64) tk0 |= (1ull<<be); else tk1 |= (1ull<<(be-64));
    }
    int myi = 0; float myd = 0.0f;
    if (lane < 32){
      int seen = 0, sel = -1;
      for (int e=0;e<cnt && sel<0;e++){
        bool s = (e<64) ? ((tk0>>e)&1ull) : ((tk1>>(e-64))&1ull);
        if (s){ if (seen == lane) sel = e; seen++; }
      }
      myi = nidx[wv][sel]; myd = nd2[wv][sel];
    }
    __builtin_amdgcn_wave_barrier();
    if (lane < 32){ nidx[wv][lane]=myi; nd2[wv][lane]=myd; }
    __builtin_amdgcn_wave_barrier();
    cnt = 32;
  }

  float in19[19];
  #pragma unroll
  for (int k=0;k<19;k++) in19[k] = 0.0f;
  if (lane < cnt){
    int j = nidx[wv][lane];
    const float4* fr = (const float4*)(F + (size_t)j*16);
    float4 a=fr[0], b=fr[1], c=fr[2], d=fr[3];
    in19[0]=a.x; in19[1]=a.y; in19[2]=a.z; in19[3]=a.w;
    in19[4]=b.x; in19[5]=b.y; in19[6]=b.z; in19[7]=b.w;
    in19[8]=c.x; in19[9]=c.y; in19[10]=c.z; in19[11]=c.w;
    in19[12]=d.x; in19[13]=d.y; in19[14]=d.z; in19[15]=d.w;
    float4 sp = spos[j];
    in19[16]=fsub_(sp.x,tp.x); in19[17]=fsub_(sp.y,tp.y); in19[18]=fsub_(sp.z,tp.z);
  }
  float h[19];
  #pragma unroll
  for (int o=0;o<19;o++){
    float acc = fmul_(in19[0], sW0[o]);
    #pragma unroll
    for (int k=1;k<19;k++) acc = fmaf(in19[k], sW0[k*19+o], acc);
    h[o] = fmaxf(fadd_(acc, sb0[o]), 0.0f);
  }
  float outv[16];
  #pragma unroll
  for (int o=0;o<16;o++){
    float acc = fmul_(h[0], sW1[o]);
    #pragma unroll
    for (int k=1;k<19;k++) acc = fmaf(h[k], sW1[k*16+o], acc);
    float v = fmaxf(fadd_(acc, sb1[o]), 0.0f);
    outv[o] = (lane < cnt) ? v : -1e30f;
  }
  #pragma unroll
  for (int o=0;o<16;o++){
    float v = outv[o];
    #pragma unroll
    for (int s=1;s<64;s<<=1) v = fmaxf(v, __shfl_xor(v, s));
    outv[o] = v;
  }
  if (lane == 0){
    float4* dst = (float4*)(Fout + (size_t)tg*16);
    dst[0] = make_float4(outv[0], outv[1], outv[2], outv[3]);
    dst[1] = make_float4(outv[4], outv[5], outv[6], outv[7]);
    dst[2] = make_float4(outv[8], outv[9], outv[10],outv[11]);
    dst[3] = make_float4(outv[12],outv[13],outv[14],outv[15]);
  }
}

// ---------------------------------------------------------------------------
// FP: wave per fine point (unchanged)
// ---------------------------------------------------------------------------
__global__ __launch_bounds__(256) void k_fp(
  const float4* __restrict__ fpos,
  const float4* __restrict__ cpos, int n_coarse,
  const float* __restrict__ Fc, const float* __restrict__ Fs,
  const float* __restrict__ W0, const float* __restrict__ b0,
  const float* __restrict__ W1, const float* __restrict__ b1,
  const float* __restrict__ loW0, const float* __restrict__ lob0,
  const float* __restrict__ loW1, const float* __restrict__ lob1,
  float* __restrict__ outp, int final_)
{
  __shared__ float sW0[1024], sb0[32], sW1[512], sb1[16];
  __shared__ float sLW0[256], sLb0[16], sLW1[32], sLb1[2];
  int tid = threadIdx.x;
  for (int i=tid;i<1024;i+=256) sW0[i]=W0[i];
  for (int i=tid;i<512;i+=256)  sW1[i]=W1[i];
  if (tid<32) sb0[tid]=b0[tid];
  if (tid<16) sb1[tid]=b1[tid];
  if (final_){
    sLW0[tid & 255] = loW0[tid & 255];
    if (tid<16) sLb0[tid]=lob0[tid];
    if (tid<32) sLW1[tid]=loW1[tid];
    if (tid<2)  sLb1[tid]=lob1[tid];
  }
  __syncthreads();

  int wv = tid >> 6, lane = tid & 63;
  int f = blockIdx.x*4 + wv;
  float4 fp = fpos[f];

  float c0v=3.5e38f, c1v=3.5e38f, c2v=3.5e38f;
  int   c0i=0x7fffffff, c1i=0x7fffffff, c2i=0x7fffffff;
  for (int j=lane; j<n_coarse; j+=64){
    float4 cp = cpos[j];
    float d2 = sqd(fp.w, cp.w, dot3(fp.x,fp.y,fp.z, cp.x,cp.y,cp.z));
    if (d2 < c2v || (d2 == c2v && j < c2i)){
      bool a0 = (d2 < c0v) || (d2 == c0v && j < c0i);
      bool a1 = (d2 < c1v) || (d2 == c1v && j < c1i);
      c2v = a1 ? c1v : d2;               c2i = a1 ? c1i : j;
      c1v = a0 ? c0v : (a1 ? d2 : c1v);  c1i = a0 ? c0i : (a1 ? j : c1i);
      c0v = a0 ? d2 : c0v;               c0i = a0 ? j  : c0i;
    }
  }
  float nnd[3]; int nni[3];
  #pragma unroll
  for (int r=0;r<3;r++){
    float v = c0v; int idx = c0i;
    #pragma unroll
    for (int s=1;s<64;s<<=1){
      float ov = __shfl_xor(v, s);
      int   oi = __shfl_xor(idx, s);
      bool tk = (ov < v) || (ov == v && oi < idx);
      v = tk ? ov : v; idx = tk ? oi : idx;
    }
    nnd[r] = v; nni[r] = idx;
    if (c0v == v && c0i == idx){
      c0v=c1v; c0i=c1i; c1v=c2v; c1i=c2i; c2v=3.5e38f; c2i=0x7fffffff;
    }
  }
  float w0 = fdiv_(1.0f, fmaxf(nnd[0], 1e-16f));
  float w1 = fdiv_(1.0f, fmaxf(nnd[1], 1e-16f));
  float w2 = fdiv_(1.0f, fmaxf(nnd[2], 1e-16f));
  float ws = fadd_(fadd_(w0,w1),w2);
  w0 = fdiv_(w0,ws); w1 = fdiv_(w1,ws); w2 = fdiv_(w2,ws);

  float hv = 0.0f;
  if (lane < 16){
    int c = lane;
    float x0 = Fc[(size_t)nni[0]*16 + c];
    float x1 = Fc[(size_t)nni[1]*16 + c];
    float x2 = Fc[(size_t)nni[2]*16 + c];
    hv = fadd_(fadd_(fmul_(w0,x0), fmul_(w1,x1)), fmul_(w2,x2));
  } else if (lane < 32){
    hv = Fs[(size_t)f*16 + (lane-16)];
  }
  int o1 = lane & 31;
  float acc = fmul_(__shfl(hv, 0), sW0[o1]);
  #pragma unroll
  for (int k=1;k<32;k++) acc = fmaf(__shfl(hv, k), sW0[k*32+o1], acc);
  float g1 = fmaxf(fadd_(acc, sb0[o1]), 0.0f);
  int o2 = lane & 15;
  float a2 = fmul_(__shfl(g1, 0), sW1[o2]);
  #pragma unroll
  for (int k=1;k<32;k++) a2 = fmaf(__shfl(g1, k), sW1[k*16+o2], a2);
  float g2 = fmaxf(fadd_(a2, sb1[o2]), 0.0f);

  if (!final_){
    if (lane < 16) outp[(size_t)f*16 + lane] = g2;
  } else {
    float a3 = fmul_(__shfl(g2, 0), sLW0[o2]);
    #pragma unroll
    for (int k=1;k<16;k++) a3 = fmaf(__shfl(g2, k), sLW0[k*16+o2], a3);
    float q = fmaxf(fadd_(a3, sLb0[o2]), 0.0f);
    int o3 = lane & 1;
    float a4 = fmul_(__shfl(q, 0), sLW1[o3]);
    #pragma unroll
    for (int k=1;k<16;k++) a4 = fmaf(__shfl(q, k), sLW1[k*2+o3], a4);
    a4 = fadd_(a4, sLb1[o3]);
    if (lane < 2) outp[(size_t)f*2 + lane] = a4;
  }
}

// ---------------------------------------------------------------------------
extern "C" void kernel_launch(void* const* d_in, const int* in_sizes, int n_in,
                              void* d_out, int out_size, void* d_ws, size_t ws_size,
                              hipStream_t stream) {
  (void)in_sizes; (void)n_in; (void)out_size; (void)ws_size;
  const float* x     = (const float*)d_in[0];
  const float* pos   = (const float*)d_in[1];
  const float* liW0  = (const float*)d_in[3];
  const float* lib0  = (const float*)d_in[4];
  const float* liW1  = (const float*)d_in[5];
  const float* lib1  = (const float*)d_in[6];
  const float* saW0  = (const float*)d_in[7];
  const float* sab0  = (const float*)d_in[8];
  const float* saW1  = (const float*)d_in[9];
  const float* sab1  = (const float*)d_in[10];
  const float* fpW0  = (const float*)d_in[11];
  const float* fpb0  = (const float*)d_in[12];
  const float* fpW1  = (const float*)d_in[13];
  const float* fpb1  = (const float*)d_in[14];
  const float* loW0  = (const float*)d_in[15];
  const float* lob0  = (const float*)d_in[16];
  const float* loW1  = (const float*)d_in[17];
  const float* lob1  = (const float*)d_in[18];
  float* out = (float*)d_out;

  char* ws = (char*)d_ws;
  size_t off = 0;
  auto alloc = [&](size_t bytes)->void* {
    void* p = ws + off;
    off += (bytes + 255) & ~(size_t)255;
    return p;
  };
  float4* P0 = (float4*)alloc(16384u*16);
  float4* P1 = (float4*)alloc(8192u*16);
  float4* P2 = (float4*)alloc(4096u*16);
  float4* P3 = (float4*)alloc(2048u*16);
  float*  F0 = (float*)alloc(16384u*16*4);
  float*  F1 = (float*)alloc(8192u*16*4);
  float*  F2 = (float*)alloc(4096u*16*4);
  float*  F3 = (float*)alloc(2048u*16*4);
  float*  G2 = (float*)alloc(4096u*16*4);
  float*  G1 = (float*)alloc(8192u*16*4);
  float4* S0 = (float4*)alloc(16384u*16);
  float4* S1 = (float4*)alloc(8192u*16);
  float4* S2 = (float4*)alloc(4096u*16);
  int*    R0 = (int*)alloc(256);

  k_prep<<<64,256,0,stream>>>(x,pos, liW0,lib0,liW1,lib1, P0,F0, 16384);

  // SA path (sort -> FPS -> group+conv per level)
  k_sort<<<1,1024,0,stream>>>(P0, S0, R0+0, 16384);
  k_fps4<16><<<1,1024,0,stream>>>(S0, R0+0, P1, 8192);
  k_sa<<<2048,256,0,stream>>>(P0,16384, P1, F0, saW0,      sab0,    saW1,      sab1,    F1);
  k_sort<<<1,1024,0,stream>>>(P1, S1, R0+1, 8192);
  k_fps4<8><<<1,1024,0,stream>>>(S1, R0+1, P2, 4096);
  k_sa<<<1024,256,0,stream>>>(P1, 8192, P2, F1, saW0+361,  sab0+19, saW1+304,  sab1+16, F2);
  k_sort<<<1,1024,0,stream>>>(P2, S2, R0+2, 4096);
  k_fps4<4><<<1,1024,0,stream>>>(S2, R0+2, P3, 2048);
  k_sa<<< 512,256,0,stream>>>(P2, 4096, P3, F2, saW0+722,  sab0+38, saW1+608,  sab1+32, F3);

  // FP path
  k_fp<<<1024,256,0,stream>>>(P2, P3,2048, F3, F2,
      fpW0+2048, fpb0+64, fpW1+1024, fpb1+32,
      loW0,lob0,loW1,lob1, G2, 0);
  k_fp<<<2048,256,0,stream>>>(P1, P2,4096, G2, F1,
      fpW0+1024, fpb0+32, fpW1+512,  fpb1+16,
      loW0,lob0,loW1,lob1, G1, 0);
  k_fp<<<4096,256,0,stream>>>(P0, P1,8192, G1, F0,
      fpW0,      fpb0,    fpW1,      fpb1,
      loW0,lob0,loW1,lob1, out, 1);
}

// Round 5
// 20558.995 us; speedup vs baseline: 2.3613x; 1.0016x over previous
//
#include <hip/hip_runtime.h>
#include <stdint.h>

// ---------------------------------------------------------------------------
// PointNet++ forward, MI355X. Round 5: pin FPS occupancy to kill the spill.
//   - k_fps5 == k_fps4 + __attribute__((amdgpu_waves_per_eu(4,4))): single
//     block of 16 waves on one CU; allocator may use 128 VGPR/wave, so the
//     per-thread point arrays live in registers (r3/r4 spilled them at the
//     compiler's 8-waves/EU occupancy target).
//   - everything else byte-identical to round 4 (validated, absmax stable).
// ---------------------------------------------------------------------------

#define DEV static __device__ __forceinline__

DEV float fadd_(float a, float b){ return __fadd_rn(a,b); }
DEV float fsub_(float a, float b){ return __fsub_rn(a,b); }
DEV float fmul_(float a, float b){ return __fmul_rn(a,b); }
DEV float fdiv_(float a, float b){ return __fdiv_rn(a,b); }

DEV float dot3(float ax,float ay,float az,float bx,float by,float bz){
  return fmaf(az,bz, fmaf(ay,by, __fmul_rn(ax,bx)));
}
DEV float sqd(float na, float nb, float d){
  float t = __fadd_rn(na, nb);
  float u = __fmul_rn(2.0f, d);
  return fmaxf(__fsub_rn(t, u), 0.0f);
}

// conservative point-to-bbox squared distance
DEV float bbd2(float sx,float sy,float sz,
               float lx,float ly,float lz,float hx,float hy,float hz){
  float dx = fmaxf(fmaxf(fsub_(lx,sx), fsub_(sx,hx)), 0.0f);
  float dy = fmaxf(fmaxf(fsub_(ly,sy), fsub_(sy,hy)), 0.0f);
  float dz = fmaxf(fmaxf(fsub_(lz,sz), fsub_(sz,hz)), 0.0f);
  return fadd_(fadd_(fmul_(dx,dx),fmul_(dy,dy)),fmul_(dz,dz));
}

// ---------------- DPP top-2 (pair-merge) reduce (validated r3/r4) ----------
#define DPP0(src, ctrl, rm, bc) \
  __builtin_amdgcn_update_dpp(0, (int)(src), (ctrl), (rm), 0xf, (bc))

#define DPP64(dst, src, ctrl, rm, bc) { \
  uint32_t lo_ = (uint32_t)DPP0((uint32_t)(src), ctrl, rm, bc); \
  uint32_t hi_ = (uint32_t)DPP0((uint32_t)((src)>>32), ctrl, rm, bc); \
  (dst) = (((unsigned long long)hi_)<<32) | lo_; }

#define MERGE2(A1, A2, ctrl, rm, bc) { \
  unsigned long long b1_, b2_, mn_, mx_; \
  DPP64(b1_, A1, ctrl, rm, bc); \
  DPP64(b2_, A2, ctrl, rm, bc); \
  mn_ = (A1) < b1_ ? (A1) : b1_; \
  mx_ = (A2) > b2_ ? (A2) : b2_; \
  (A1) = (A1) > b1_ ? (A1) : b1_; \
  (A2) = mn_ > mx_ ? mn_ : mx_; }

DEV unsigned long long rdlane64(unsigned long long v, int l){
  uint32_t lo=(uint32_t)__builtin_amdgcn_readlane((int)(uint32_t)v, l);
  uint32_t hi=(uint32_t)__builtin_amdgcn_readlane((int)(uint32_t)(v>>32), l);
  return (((unsigned long long)hi)<<32)|lo;
}

DEV void wtop2(unsigned long long &A1, unsigned long long &A2){  // 64 lanes
  MERGE2(A1,A2,0x111,0xf,true)
  MERGE2(A1,A2,0x112,0xf,true)
  MERGE2(A1,A2,0x114,0xf,true)
  MERGE2(A1,A2,0x118,0xf,true)
  MERGE2(A1,A2,0x142,0xa,false)
  MERGE2(A1,A2,0x143,0xc,false)
  A1 = rdlane64(A1,63); A2 = rdlane64(A2,63);
}
DEV void htop2(unsigned long long &A1, unsigned long long &A2){  // lanes 0..31
  MERGE2(A1,A2,0x111,0xf,true)
  MERGE2(A1,A2,0x112,0xf,true)
  MERGE2(A1,A2,0x114,0xf,true)
  MERGE2(A1,A2,0x118,0xf,true)
  MERGE2(A1,A2,0x142,0xa,false)
  A1 = rdlane64(A1,31); A2 = rdlane64(A2,31);
}

// ---------------------------------------------------------------------------
// prep: pos -> float4(x,y,z,|p|^2)  and  h0 = lin_in MLP(x)
// ---------------------------------------------------------------------------
__global__ __launch_bounds__(256) void k_prep(
    const float* __restrict__ x, const float* __restrict__ pos,
    const float* __restrict__ W0, const float* __restrict__ b0,
    const float* __restrict__ W1, const float* __restrict__ b1,
    float4* __restrict__ pos4, float* __restrict__ h_out, int n)
{
  __shared__ float sW0[256], sb0[16], sW1[256], sb1[16];
  int tid = threadIdx.x;
  sW0[tid] = W0[tid];
  sW1[tid] = W1[tid];
  if (tid < 16){ sb0[tid] = b0[tid]; sb1[tid] = b1[tid]; }
  __syncthreads();
  int p = blockIdx.x*256 + tid;
  if (p >= n) return;

  float px = pos[3*p], py = pos[3*p+1], pz = pos[3*p+2];
  float nrm = fadd_(fadd_(fmul_(px,px), fmul_(py,py)), fmul_(pz,pz));
  pos4[p] = make_float4(px,py,pz,nrm);

  const float4* xr = (const float4*)(x + (size_t)p*16);
  float4 v0 = xr[0], v1 = xr[1], v2 = xr[2], v3 = xr[3];
  float xin[16] = {v0.x,v0.y,v0.z,v0.w, v1.x,v1.y,v1.z,v1.w,
                   v2.x,v2.y,v2.z,v2.w, v3.x,v3.y,v3.z,v3.w};
  float h1[16];
  #pragma unroll
  for (int o=0;o<16;o++){
    float acc = fmul_(xin[0], sW0[o]);
    #pragma unroll
    for (int k=1;k<16;k++) acc = fmaf(xin[k], sW0[k*16+o], acc);
    h1[o] = fmaxf(fadd_(acc, sb0[o]), 0.0f);
  }
  float h2[16];
  #pragma unroll
  for (int o=0;o<16;o++){
    float acc = fmul_(h1[0], sW1[o]);
    #pragma unroll
    for (int k=1;k<16;k++) acc = fmaf(h1[k], sW1[k*16+o], acc);
    h2[o] = fmaxf(fadd_(acc, sb1[o]), 0.0f);
  }
  float4* hw = (float4*)(h_out + (size_t)p*16);
  hw[0] = make_float4(h2[0], h2[1], h2[2], h2[3]);
  hw[1] = make_float4(h2[4], h2[5], h2[6], h2[7]);
  hw[2] = make_float4(h2[8], h2[9], h2[10],h2[11]);
  hw[3] = make_float4(h2[12],h2[13],h2[14],h2[15]);
}

// ---------------------------------------------------------------------------
// k_sort: Morton counting sort (16^3 cells). Output w = bits(natural index).
// ---------------------------------------------------------------------------
DEV uint32_t expand4(uint32_t v){
  return (v&1u) | ((v&2u)<<2) | ((v&4u)<<4) | ((v&8u)<<6);
}
DEV int cellc(float v){
  int c = (int)(v*0.5f);
  return c < 0 ? 0 : (c > 15 ? 15 : c);
}
DEV uint32_t mkey(float4 p){
  return expand4((uint32_t)cellc(p.x))
       | (expand4((uint32_t)cellc(p.y))<<1)
       | (expand4((uint32_t)cellc(p.z))<<2);
}

__global__ __launch_bounds__(1024) void k_sort(
  const float4* __restrict__ nat, float4* __restrict__ srt,
  int* __restrict__ rank0, int n)
{
  __shared__ uint32_t hist[4096];
  __shared__ uint32_t gsum[1024];
  int tid = threadIdx.x;
  for (int i=tid;i<4096;i+=1024) hist[i]=0u;
  __syncthreads();
  for (int i=tid;i<n;i+=1024){
    float4 p = nat[i];
    atomicAdd(&hist[mkey(p)], 1u);
  }
  __syncthreads();
  uint32_t h0=hist[4*tid],h1=hist[4*tid+1],h2=hist[4*tid+2],h3=hist[4*tid+3];
  gsum[tid] = h0+h1+h2+h3;
  __syncthreads();
  for (int off=1; off<1024; off<<=1){
    uint32_t v = gsum[tid];
    uint32_t a = (tid>=off)? gsum[tid-off] : 0u;
    __syncthreads();
    gsum[tid] = v + a;
    __syncthreads();
  }
  uint32_t excl = (tid>0)? gsum[tid-1] : 0u;
  hist[4*tid]   = excl;
  hist[4*tid+1] = excl + h0;
  hist[4*tid+2] = excl + h0 + h1;
  hist[4*tid+3] = excl + h0 + h1 + h2;
  __syncthreads();
  for (int i=tid;i<n;i+=1024){
    float4 p = nat[i];
    uint32_t r = atomicAdd(&hist[mkey(p)], 1u);
    srt[r] = make_float4(p.x, p.y, p.z, __uint_as_float((uint32_t)i));
    if (i==0) *rank0 = (int)r;
  }
}

// ---------------------------------------------------------------------------
// k_fps5: thread-parallel pruned FPS (== k_fps4 algorithm, occupancy-pinned).
// amdgpu_waves_per_eu(4,4): exactly 16 waves/CU -> 128 VGPR/wave available,
// so px/py/pz/klo stay in registers (no scratch).
// ---------------------------------------------------------------------------
template<int P>
__global__ __attribute__((amdgpu_waves_per_eu(4,4)))
__launch_bounds__(1024) void k_fps5(
    const float4* __restrict__ sp4,   // sorted points, w = bits(natidx)
    const int* __restrict__ rank0p,
    float4* __restrict__ samp,        // selection-order output, w = |p|^2
    int m)
{
  __shared__ float smind[P*1024];
  __shared__ uint32_t xch[2][32*5];   // [parity][slot*5 + {klo,khi,x,y,z}]
  const int t = threadIdx.x;
  const int lane = t & 63;
  const int w = t >> 6;

  float px[P], py[P], pz[P];
  uint32_t klo[P];
  float blox,bloy,bloz,bhix,bhiy,bhiz;
  #pragma unroll
  for (int k=0;k<P;k++){
    float4 p = sp4[t*P+k];
    px[k]=p.x; py[k]=p.y; pz[k]=p.z;
    uint32_t nat = __float_as_uint(p.w);
    klo[k] = ((0x3FFFu - nat)<<16) | (uint32_t)(t*P+k);
    smind[k*1024+t] = __builtin_inff();
    if (k==0){ blox=bhix=p.x; bloy=bhiy=p.y; bloz=bhiz=p.z; }
    else {
      blox=fminf(blox,p.x); bhix=fmaxf(bhix,p.x);
      bloy=fminf(bloy,p.y); bhiy=fmaxf(bhiy,p.y);
      bloz=fminf(bloz,p.z); bhiz=fmaxf(bhiz,p.z);
    }
  }

  float c1x,c1y,c1z, c2x=0.f,c2y=0.f,c2z=0.f;
  {
    int r0 = *rank0p;
    float4 s0 = sp4[r0];
    c1x=s0.x; c1y=s0.y; c1z=s0.z;
    if (t==0){
      float nr = fadd_(fadd_(fmul_(s0.x,s0.x),fmul_(s0.y,s0.y)),fmul_(s0.z,s0.z));
      samp[0] = make_float4(s0.x,s0.y,s0.z,nr);
    }
  }
  __syncthreads();

  // thread champions; hi=inf forces round-0 update for every thread
  unsigned long long tc1 = ((unsigned long long)0x7f800000u)<<32, tc2 = 0ull;
  // cached owner slots (valid after round 0)
  bool own1 = false, own2 = false;
  uint32_t c1lo=0,c1hi=0, c2lo=0,c2hi=0;
  float o1x=0,o1y=0,o1z=0, o2x=0,o2y=0,o2z=0;

  int u2 = 0, sel = 1, round = 0;

  while (true){
    // ---- thread-local skip test ------------------------------------------
    bool updp;
    {
      float cv = __uint_as_float((uint32_t)(tc1>>32));
      float dm = bbd2(c1x,c1y,c1z, blox,bloy,bloz,bhix,bhiy,bhiz);
      if (u2){
        float dd = bbd2(c2x,c2y,c2z, blox,bloy,bloz,bhix,bhiy,bhiz);
        dm = fminf(dm, dd);
      }
      updp = (fmul_(dm, 0.99999f) < cv);
    }
    // ---- update + wave reduce + owner refresh only where needed ----------
    if (__ballot(updp) != 0ull){
      if (updp){
        tc1 = 0ull; tc2 = 0ull;
        #pragma unroll
        for (int k=0;k<P;k++){
          float dx=fsub_(px[k],c1x), dy=fsub_(py[k],c1y), dz=fsub_(pz[k],c1z);
          float da = fadd_(fadd_(fmul_(dx,dx),fmul_(dy,dy)),fmul_(dz,dz));
          float nm = fminf(smind[k*1024+t], da);
          if (u2){
            float ex=fsub_(px[k],c2x), ey=fsub_(py[k],c2y), ez=fsub_(pz[k],c2z);
            float db = fadd_(fadd_(fmul_(ex,ex),fmul_(ey,ey)),fmul_(ez,ez));
            nm = fminf(nm, db);
          }
          smind[k*1024+t] = nm;
          unsigned long long key =
            (((unsigned long long)__float_as_uint(nm))<<32) | klo[k];
          bool g1 = key > tc1;
          unsigned long long nt2 = g1 ? tc1 : (key > tc2 ? key : tc2);
          tc1 = g1 ? key : tc1;
          tc2 = nt2;
        }
      }
      unsigned long long a1 = tc1, a2 = tc2;
      wtop2(a1, a2);
      // refresh owner caches (whole wave)
      own1 = (tc1 == a1);
      own2 = (tc1 == a2) || (tc2 == a2);
      int kk1 = (int)(a1 & (unsigned long long)(P-1));
      int kk2 = (int)(a2 & (unsigned long long)(P-1));
      float sx1=px[0], sy1=py[0], sz1=pz[0];
      float sx2=px[0], sy2=py[0], sz2=pz[0];
      #pragma unroll
      for (int j=1;j<P;j++){
        bool e1=(j==kk1), e2=(j==kk2);
        sx1=e1?px[j]:sx1; sy1=e1?py[j]:sy1; sz1=e1?pz[j]:sz1;
        sx2=e2?px[j]:sx2; sy2=e2?py[j]:sy2; sz2=e2?pz[j]:sz2;
      }
      c1lo=(uint32_t)a1; c1hi=(uint32_t)(a1>>32); o1x=sx1; o1y=sy1; o1z=sz1;
      c2lo=(uint32_t)a2; c2hi=(uint32_t)(a2>>32); o2x=sx2; o2y=sy2; o2z=sz2;
    }
    // ---- publish wave candidates (owners rewrite every round) ------------
    int par = round & 1;
    if (own1){
      int b = (w*2)*5;
      xch[par][b]=c1lo; xch[par][b+1]=c1hi;
      xch[par][b+2]=__float_as_uint(o1x);
      xch[par][b+3]=__float_as_uint(o1y);
      xch[par][b+4]=__float_as_uint(o1z);
    }
    if (own2){
      int b = (w*2+1)*5;
      xch[par][b]=c2lo; xch[par][b+1]=c2hi;
      xch[par][b+2]=__float_as_uint(o2x);
      xch[par][b+3]=__float_as_uint(o2y);
      xch[par][b+4]=__float_as_uint(o2z);
    }
    __syncthreads();
    // ---- global top-2 over 32 slots (all waves redundantly) --------------
    unsigned long long cnd = 0ull;
    if (lane < 32){
      uint32_t lo = xch[par][lane*5], hi = xch[par][lane*5+1];
      cnd = (((unsigned long long)hi)<<32) | lo;
    }
    unsigned long long a1 = cnd, a2 = 0ull;
    htop2(a1, a2);
    unsigned long long b1 = __ballot(lane<32 && cnd==a1);
    unsigned long long b2 = __ballot(lane<32 && cnd==a2);
    int s1 = __ffsll(b1)-1;
    int s2 = __ffsll(b2)-1;
    float p1x=__uint_as_float(xch[par][s1*5+2]);
    float p1y=__uint_as_float(xch[par][s1*5+3]);
    float p1z=__uint_as_float(xch[par][s1*5+4]);
    float p2x=__uint_as_float(xch[par][s2*5+2]);
    float p2y=__uint_as_float(xch[par][s2*5+3]);
    float p2z=__uint_as_float(xch[par][s2*5+4]);
    float v2 = __uint_as_float((uint32_t)(a2>>32));
    // ---- exact double-accept ---------------------------------------------
    float qx=fsub_(p2x,p1x), qy=fsub_(p2y,p1y), qz=fsub_(p2z,p1z);
    float q  = fadd_(fadd_(fmul_(qx,qx),fmul_(qy,qy)),fmul_(qz,qz));
    bool acc2 = (sel+1 < m) && (q >= v2);
    if (t==0){
      float nr = fadd_(fadd_(fmul_(p1x,p1x),fmul_(p1y,p1y)),fmul_(p1z,p1z));
      samp[sel] = make_float4(p1x,p1y,p1z,nr);
    }
    if (acc2 && t==1){
      float nr = fadd_(fadd_(fmul_(p2x,p2x),fmul_(p2y,p2y)),fmul_(p2z,p2z));
      samp[sel+1] = make_float4(p2x,p2y,p2z,nr);
    }
    sel += acc2 ? 2 : 1;
    round++;
    if (sel >= m) break;
    c1x=p1x; c1y=p1y; c1z=p1z;
    u2 = acc2 ? 1 : 0;
    if (acc2){ c2x=p2x; c2y=p2y; c2z=p2z; }
  }
}

// ---------------------------------------------------------------------------
// SA: wave per target (unchanged)
// ---------------------------------------------------------------------------
#define SA_CAP 96

__global__ __launch_bounds__(256) void k_sa(
  const float4* __restrict__ spos, int n_src,
  const float4* __restrict__ tpos,
  const float*  __restrict__ F,
  const float* __restrict__ W0, const float* __restrict__ b0,
  const float* __restrict__ W1, const float* __restrict__ b1,
  float* __restrict__ Fout)
{
  __shared__ float sW0[361], sb0[19], sW1[304], sb1[16];
  __shared__ int   nidx[4][SA_CAP];
  __shared__ float nd2[4][SA_CAP];
  int tid = threadIdx.x;
  for (int i=tid;i<361;i+=256) sW0[i]=W0[i];
  for (int i=tid;i<304;i+=256) sW1[i]=W1[i];
  if (tid<19) sb0[tid]=b0[tid];
  if (tid<16) sb1[tid]=b1[tid];
  __syncthreads();

  int wv = tid >> 6, lane = tid & 63;
  int tg = blockIdx.x*4 + wv;
  float4 tp = tpos[tg];

  int cnt = 0;
  for (int base=0; base<n_src; base+=64){
    int j = base + lane;
    float4 sp = spos[j];
    float d2 = sqd(tp.w, sp.w, dot3(tp.x,tp.y,tp.z, sp.x,sp.y,sp.z));
    bool in = (d2 <= 4.0f);
    unsigned long long mk = __ballot(in);
    int pos = cnt + __popcll(mk & ((1ull<<lane)-1ull));
    if (in && pos < SA_CAP){ nidx[wv][pos]=j; nd2[wv][pos]=d2; }
    cnt += __popcll(mk);
  }
  if (cnt > SA_CAP) cnt = SA_CAP;

  if (cnt > 32){
    uint64_t tk0=0, tk1=0;
    for (int r=0;r<32;r++){
      float bvv = 3.5e38f; int bii = 0x7fffffff; int be = 0;
      for (int e=0;e<cnt;e++){
        bool done = (e<64) ? ((tk0>>e)&1ull) : ((tk1>>(e-64))&1ull);
        if (done) continue;
        float dv = nd2[wv][e]; int di = nidx[wv][e];
        if (dv < bvv || (dv == bvv && di < bii)){ bvv=dv; bii=di; be=e; }
      }
      if (be < 64) tk0 |= (1ull<<be); else tk1 |= (1ull<<(be-64));
    }
    int myi = 0; float myd = 0.0f;
    if (lane < 32){
      int seen = 0, sel = -1;
      for (int e=0;e<cnt && sel<0;e++){
        bool s = (e<64) ? ((tk0>>e)&1ull) : ((tk1>>(e-64))&1ull);
        if (s){ if (seen == lane) sel = e; seen++; }
      }
      myi = nidx[wv][sel]; myd = nd2[wv][sel];
    }
    __builtin_amdgcn_wave_barrier();
    if (lane < 32){ nidx[wv][lane]=myi; nd2[wv][lane]=myd; }
    __builtin_amdgcn_wave_barrier();
    cnt = 32;
  }

  float in19[19];
  #pragma unroll
  for (int k=0;k<19;k++) in19[k] = 0.0f;
  if (lane < cnt){
    int j = nidx[wv][lane];
    const float4* fr = (const float4*)(F + (size_t)j*16);
    float4 a=fr[0], b=fr[1], c=fr[2], d=fr[3];
    in19[0]=a.x; in19[1]=a.y; in19[2]=a.z; in19[3]=a.w;
    in19[4]=b.x; in19[5]=b.y; in19[6]=b.z; in19[7]=b.w;
    in19[8]=c.x; in19[9]=c.y; in19[10]=c.z; in19[11]=c.w;
    in19[12]=d.x; in19[13]=d.y; in19[14]=d.z; in19[15]=d.w;
    float4 sp = spos[j];
    in19[16]=fsub_(sp.x,tp.x); in19[17]=fsub_(sp.y,tp.y); in19[18]=fsub_(sp.z,tp.z);
  }
  float h[19];
  #pragma unroll
  for (int o=0;o<19;o++){
    float acc = fmul_(in19[0], sW0[o]);
    #pragma unroll
    for (int k=1;k<19;k++) acc = fmaf(in19[k], sW0[k*19+o], acc);
    h[o] = fmaxf(fadd_(acc, sb0[o]), 0.0f);
  }
  float outv[16];
  #pragma unroll
  for (int o=0;o<16;o++){
    float acc = fmul_(h[0], sW1[o]);
    #pragma unroll
    for (int k=1;k<19;k++) acc = fmaf(h[k], sW1[k*16+o], acc);
    float v = fmaxf(fadd_(acc, sb1[o]), 0.0f);
    outv[o] = (lane < cnt) ? v : -1e30f;
  }
  #pragma unroll
  for (int o=0;o<16;o++){
    float v = outv[o];
    #pragma unroll
    for (int s=1;s<64;s<<=1) v = fmaxf(v, __shfl_xor(v, s));
    outv[o] = v;
  }
  if (lane == 0){
    float4* dst = (float4*)(Fout + (size_t)tg*16);
    dst[0] = make_float4(outv[0], outv[1], outv[2], outv[3]);
    dst[1] = make_float4(outv[4], outv[5], outv[6], outv[7]);
    dst[2] = make_float4(outv[8], outv[9], outv[10],outv[11]);
    dst[3] = make_float4(outv[12],outv[13],outv[14],outv[15]);
  }
}

// ---------------------------------------------------------------------------
// FP: wave per fine point (unchanged)
// ---------------------------------------------------------------------------
__global__ __launch_bounds__(256) void k_fp(
  const float4* __restrict__ fpos,
  const float4* __restrict__ cpos, int n_coarse,
  const float* __restrict__ Fc, const float* __restrict__ Fs,
  const float* __restrict__ W0, const float* __restrict__ b0,
  const float* __restrict__ W1, const float* __restrict__ b1,
  const float* __restrict__ loW0, const float* __restrict__ lob0,
  const float* __restrict__ loW1, const float* __restrict__ lob1,
  float* __restrict__ outp, int final_)
{
  __shared__ float sW0[1024], sb0[32], sW1[512], sb1[16];
  __shared__ float sLW0[256], sLb0[16], sLW1[32], sLb1[2];
  int tid = threadIdx.x;
  for (int i=tid;i<1024;i+=256) sW0[i]=W0[i];
  for (int i=tid;i<512;i+=256)  sW1[i]=W1[i];
  if (tid<32) sb0[tid]=b0[tid];
  if (tid<16) sb1[tid]=b1[tid];
  if (final_){
    sLW0[tid & 255] = loW0[tid & 255];
    if (tid<16) sLb0[tid]=lob0[tid];
    if (tid<32) sLW1[tid]=loW1[tid];
    if (tid<2)  sLb1[tid]=lob1[tid];
  }
  __syncthreads();

  int wv = tid >> 6, lane = tid & 63;
  int f = blockIdx.x*4 + wv;
  float4 fp = fpos[f];

  float c0v=3.5e38f, c1v=3.5e38f, c2v=3.5e38f;
  int   c0i=0x7fffffff, c1i=0x7fffffff, c2i=0x7fffffff;
  for (int j=lane; j<n_coarse; j+=64){
    float4 cp = cpos[j];
    float d2 = sqd(fp.w, cp.w, dot3(fp.x,fp.y,fp.z, cp.x,cp.y,cp.z));
    if (d2 < c2v || (d2 == c2v && j < c2i)){
      bool a0 = (d2 < c0v) || (d2 == c0v && j < c0i);
      bool a1 = (d2 < c1v) || (d2 == c1v && j < c1i);
      c2v = a1 ? c1v : d2;               c2i = a1 ? c1i : j;
      c1v = a0 ? c0v : (a1 ? d2 : c1v);  c1i = a0 ? c0i : (a1 ? j : c1i);
      c0v = a0 ? d2 : c0v;               c0i = a0 ? j  : c0i;
    }
  }
  float nnd[3]; int nni[3];
  #pragma unroll
  for (int r=0;r<3;r++){
    float v = c0v; int idx = c0i;
    #pragma unroll
    for (int s=1;s<64;s<<=1){
      float ov = __shfl_xor(v, s);
      int   oi = __shfl_xor(idx, s);
      bool tk = (ov < v) || (ov == v && oi < idx);
      v = tk ? ov : v; idx = tk ? oi : idx;
    }
    nnd[r] = v; nni[r] = idx;
    if (c0v == v && c0i == idx){
      c0v=c1v; c0i=c1i; c1v=c2v; c1i=c2i; c2v=3.5e38f; c2i=0x7fffffff;
    }
  }
  float w0 = fdiv_(1.0f, fmaxf(nnd[0], 1e-16f));
  float w1 = fdiv_(1.0f, fmaxf(nnd[1], 1e-16f));
  float w2 = fdiv_(1.0f, fmaxf(nnd[2], 1e-16f));
  float ws = fadd_(fadd_(w0,w1),w2);
  w0 = fdiv_(w0,ws); w1 = fdiv_(w1,ws); w2 = fdiv_(w2,ws);

  float hv = 0.0f;
  if (lane < 16){
    int c = lane;
    float x0 = Fc[(size_t)nni[0]*16 + c];
    float x1 = Fc[(size_t)nni[1]*16 + c];
    float x2 = Fc[(size_t)nni[2]*16 + c];
    hv = fadd_(fadd_(fmul_(w0,x0), fmul_(w1,x1)), fmul_(w2,x2));
  } else if (lane < 32){
    hv = Fs[(size_t)f*16 + (lane-16)];
  }
  int o1 = lane & 31;
  float acc = fmul_(__shfl(hv, 0), sW0[o1]);
  #pragma unroll
  for (int k=1;k<32;k++) acc = fmaf(__shfl(hv, k), sW0[k*32+o1], acc);
  float g1 = fmaxf(fadd_(acc, sb0[o1]), 0.0f);
  int o2 = lane & 15;
  float a2 = fmul_(__shfl(g1, 0), sW1[o2]);
  #pragma unroll
  for (int k=1;k<32;k++) a2 = fmaf(__shfl(g1, k), sW1[k*16+o2], a2);
  float g2 = fmaxf(fadd_(a2, sb1[o2]), 0.0f);

  if (!final_){
    if (lane < 16) outp[(size_t)f*16 + lane] = g2;
  } else {
    float a3 = fmul_(__shfl(g2, 0), sLW0[o2]);
    #pragma unroll
    for (int k=1;k<16;k++) a3 = fmaf(__shfl(g2, k), sLW0[k*16+o2], a3);
    float q = fmaxf(fadd_(a3, sLb0[o2]), 0.0f);
    int o3 = lane & 1;
    float a4 = fmul_(__shfl(q, 0), sLW1[o3]);
    #pragma unroll
    for (int k=1;k<16;k++) a4 = fmaf(__shfl(q, k), sLW1[k*2+o3], a4);
    a4 = fadd_(a4, sLb1[o3]);
    if (lane < 2) outp[(size_t)f*2 + lane] = a4;
  }
}

// ---------------------------------------------------------------------------
extern "C" void kernel_launch(void* const* d_in, const int* in_sizes, int n_in,
                              void* d_out, int out_size, void* d_ws, size_t ws_size,
                              hipStream_t stream) {
  (void)in_sizes; (void)n_in; (void)out_size; (void)ws_size;
  const float* x     = (const float*)d_in[0];
  const float* pos   = (const float*)d_in[1];
  const float* liW0  = (const float*)d_in[3];
  const float* lib0  = (const float*)d_in[4];
  const float* liW1  = (const float*)d_in[5];
  const float* lib1  = (const float*)d_in[6];
  const float* saW0  = (const float*)d_in[7];
  const float* sab0  = (const float*)d_in[8];
  const float* saW1  = (const float*)d_in[9];
  const float* sab1  = (const float*)d_in[10];
  const float* fpW0  = (const float*)d_in[11];
  const float* fpb0  = (const float*)d_in[12];
  const float* fpW1  = (const float*)d_in[13];
  const float* fpb1  = (const float*)d_in[14];
  const float* loW0  = (const float*)d_in[15];
  const float* lob0  = (const float*)d_in[16];
  const float* loW1  = (const float*)d_in[17];
  const float* lob1  = (const float*)d_in[18];
  float* out = (float*)d_out;

  char* ws = (char*)d_ws;
  size_t off = 0;
  auto alloc = [&](size_t bytes)->void* {
    void* p = ws + off;
    off += (bytes + 255) & ~(size_t)255;
    return p;
  };
  float4* P0 = (float4*)alloc(16384u*16);
  float4* P1 = (float4*)alloc(8192u*16);
  float4* P2 = (float4*)alloc(4096u*16);
  float4* P3 = (float4*)alloc(2048u*16);
  float*  F0 = (float*)alloc(16384u*16*4);
  float*  F1 = (float*)alloc(8192u*16*4);
  float*  F2 = (float*)alloc(4096u*16*4);
  float*  F3 = (float*)alloc(2048u*16*4);
  float*  G2 = (float*)alloc(4096u*16*4);
  float*  G1 = (float*)alloc(8192u*16*4);
  float4* S0 = (float4*)alloc(16384u*16);
  float4* S1 = (float4*)alloc(8192u*16);
  float4* S2 = (float4*)alloc(4096u*16);
  int*    R0 = (int*)alloc(256);

  k_prep<<<64,256,0,stream>>>(x,pos, liW0,lib0,liW1,lib1, P0,F0, 16384);

  // SA path (sort -> FPS -> group+conv per level)
  k_sort<<<1,1024,0,stream>>>(P0, S0, R0+0, 16384);
  k_fps5<16><<<1,1024,0,stream>>>(S0, R0+0, P1, 8192);
  k_sa<<<2048,256,0,stream>>>(P0,16384, P1, F0, saW0,      sab0,    saW1,      sab1,    F1);
  k_sort<<<1,1024,0,stream>>>(P1, S1, R0+1, 8192);
  k_fps5<8><<<1,1024,0,stream>>>(S1, R0+1, P2, 4096);
  k_sa<<<1024,256,0,stream>>>(P1, 8192, P2, F1, saW0+361,  sab0+19, saW1+304,  sab1+16, F2);
  k_sort<<<1,1024,0,stream>>>(P2, S2, R0+2, 4096);
  k_fps5<4><<<1,1024,0,stream>>>(S2, R0+2, P3, 2048);
  k_sa<<< 512,256,0,stream>>>(P2, 4096, P3, F2, saW0+722,  sab0+38, saW1+608,  sab1+32, F3);

  // FP path
  k_fp<<<1024,256,0,stream>>>(P2, P3,2048, F3, F2,
      fpW0+2048, fpb0+64, fpW1+1024, fpb1+32,
      loW0,lob0,loW1,lob1, G2, 0);
  k_fp<<<2048,256,0,stream>>>(P1, P2,4096, G2, F1,
      fpW0+1024, fpb0+32, fpW1+512,  fpb1+16,
      loW0,lob0,loW1,lob1, G1, 0);
  k_fp<<<4096,256,0,stream>>>(P0, P1,8192, G1, F0,
      fpW0,      fpb0,    fpW1,      fpb1,
      loW0,lob0,loW1,lob1, out, 1);
}